// Round 6
// baseline (580.226 us; speedup 1.0000x reference)
//
#include <hip/hip_runtime.h>
#include <hip/hip_bf16.h>
#include <float.h>

// Problem constants (from reference)
#define N_NODES 20000
#define LATENT  512
#define HID     256
#define OUT_C   128
#define HEADS   2
#define HC      256   // HEADS*OUT_C
#define NEG_SLOPE 0.2f

typedef __attribute__((ext_vector_type(8))) short short8;  // 8 bf16 = 4 VGPRs
typedef __attribute__((ext_vector_type(4))) float f32x4;

// ---------------------------------------------------------------------------
__device__ __forceinline__ ushort f2bf(float v) {
    __hip_bfloat16 h = __float2bfloat16(v);
    return *(ushort*)&h;
}
__device__ __forceinline__ float bf2f(ushort u) {
    __hip_bfloat16 h = *(__hip_bfloat16*)&u;
    return __bfloat162float(h);
}
__device__ __forceinline__ float bfu(ushort u) {   // exact bf16 -> fp32
    return __uint_as_float((unsigned)u << 16);
}
__device__ __forceinline__ void split2(float v, ushort& hi, ushort& lo) {
    hi = f2bf(v);
    lo = f2bf(v - bf2f(hi));
}

// ---------------------------------------------------------------------------
// Split-bf16 MFMA GEMM:  C = act( Ah*Bh + Ah*Bl + Al*Bh + bias )
// A [M,K] hi/lo bf16 row-major; B TRANSPOSED: BT [N,K] hi/lo bf16.
// Block tile BMT x 128, 4 waves ((BMT/2)x64 each), BK=32.
// Outputs: fp32 Cf, and/or bf16 C_hi (+ optional C_lo for split).
#define ST 40   // LDS row stride in shorts (32+8 pad -> <=2-way bank alias, free)

template<int BMT>
__global__ __launch_bounds__(256) void gemm_split_mfma(
    const ushort* __restrict__ A_hi, const ushort* __restrict__ A_lo,
    const ushort* __restrict__ BT_hi, const ushort* __restrict__ BT_lo,
    const float* __restrict__ bias,
    float* __restrict__ Cf, ushort* __restrict__ C_hi, ushort* __restrict__ C_lo,
    int M, int N, int K, int relu)
{
    constexpr int MI   = BMT / 32;   // M frags per wave (16-rows each)
    constexpr int A_LD = BMT / 64;   // int4 loads per thread per A array
    __shared__ ushort lds[(2 * BMT + 2 * 128) * ST];

    ushort* ldsAh = lds;
    ushort* ldsAl = lds + BMT * ST;
    ushort* ldsBh = lds + 2 * BMT * ST;
    ushort* ldsBl = lds + 2 * BMT * ST + 128 * ST;

    const int t = threadIdx.x;
    const int l = t & 63;
    const int w = t >> 6;
    const int wm = (w >> 1) * (BMT / 2);   // wave M offset in tile
    const int wn = (w & 1) * 64;           // wave N offset in tile
    const int lm = l & 15;
    const int q8 = (l >> 4) * 8;           // frag k offset
    const int q4 = (l >> 4) * 4;           // C frag row offset

    const int row0 = blockIdx.x * BMT;
    const int col0 = blockIdx.y * 128;

    // staging: load id = i*256 + t -> row = id>>2 (= srow + i*64), col = (t&3)*8
    const int srow = t >> 2;
    const int scol = (t & 3) * 8;

    const ushort* pAh = A_hi + (size_t)(row0 + srow) * K + scol;
    const ushort* pAl = A_lo + (size_t)(row0 + srow) * K + scol;
    const ushort* pBh = BT_hi + (size_t)(col0 + srow) * K + scol;
    const ushort* pBl = BT_lo + (size_t)(col0 + srow) * K + scol;

    bool a_ok[A_LD];
    #pragma unroll
    for (int i = 0; i < A_LD; ++i) a_ok[i] = (row0 + srow + i * 64) < M;

    const f32x4 zf = {0.f, 0.f, 0.f, 0.f};
    f32x4 acc[MI][4];
    #pragma unroll
    for (int i = 0; i < MI; ++i)
        #pragma unroll
        for (int j = 0; j < 4; ++j) acc[i][j] = zf;

    const int4 zero4 = make_int4(0, 0, 0, 0);
    int4 ra_h[A_LD], ra_l[A_LD], rb_h[2], rb_l[2];
    #pragma unroll
    for (int i = 0; i < A_LD; ++i) {
        ra_h[i] = a_ok[i] ? *(const int4*)(pAh + (size_t)i * 64 * K) : zero4;
        ra_l[i] = a_ok[i] ? *(const int4*)(pAl + (size_t)i * 64 * K) : zero4;
    }
    #pragma unroll
    for (int i = 0; i < 2; ++i) {
        rb_h[i] = *(const int4*)(pBh + (size_t)i * 64 * K);
        rb_l[i] = *(const int4*)(pBl + (size_t)i * 64 * K);
    }

    for (int k0 = 0; k0 < K; k0 += 32) {
        __syncthreads();   // previous iteration's frag reads done
        #pragma unroll
        for (int i = 0; i < A_LD; ++i) {
            *(int4*)&ldsAh[(srow + i * 64) * ST + scol] = ra_h[i];
            *(int4*)&ldsAl[(srow + i * 64) * ST + scol] = ra_l[i];
        }
        #pragma unroll
        for (int i = 0; i < 2; ++i) {
            *(int4*)&ldsBh[(srow + i * 64) * ST + scol] = rb_h[i];
            *(int4*)&ldsBl[(srow + i * 64) * ST + scol] = rb_l[i];
        }
        __syncthreads();

        if (k0 + 32 < K) {   // prefetch next chunk while MFMAs run
            const int kk = k0 + 32;
            #pragma unroll
            for (int i = 0; i < A_LD; ++i) {
                ra_h[i] = a_ok[i] ? *(const int4*)(pAh + (size_t)i * 64 * K + kk) : zero4;
                ra_l[i] = a_ok[i] ? *(const int4*)(pAl + (size_t)i * 64 * K + kk) : zero4;
            }
            #pragma unroll
            for (int i = 0; i < 2; ++i) {
                rb_h[i] = *(const int4*)(pBh + (size_t)i * 64 * K + kk);
                rb_l[i] = *(const int4*)(pBl + (size_t)i * 64 * K + kk);
            }
        }

        short8 bh[4], bl[4];
        #pragma unroll
        for (int ni = 0; ni < 4; ++ni) {
            const int boff = (wn + ni * 16 + lm) * ST + q8;
            bh[ni] = *(const short8*)&ldsBh[boff];
            bl[ni] = *(const short8*)&ldsBl[boff];
        }
        #pragma unroll
        for (int mi = 0; mi < MI; ++mi) {
            const int aoff = (wm + mi * 16 + lm) * ST + q8;
            short8 ah = *(const short8*)&ldsAh[aoff];
            short8 al = *(const short8*)&ldsAl[aoff];
            #pragma unroll
            for (int ni = 0; ni < 4; ++ni) {
                acc[mi][ni] = __builtin_amdgcn_mfma_f32_16x16x32_bf16(ah, bh[ni], acc[mi][ni], 0, 0, 0);
                acc[mi][ni] = __builtin_amdgcn_mfma_f32_16x16x32_bf16(ah, bl[ni], acc[mi][ni], 0, 0, 0);
                acc[mi][ni] = __builtin_amdgcn_mfma_f32_16x16x32_bf16(al, bh[ni], acc[mi][ni], 0, 0, 0);
            }
        }
    }

    // Epilogue. C/D frag: col = lane&15, row = (lane>>4)*4 + reg  [m89/m91]
    #pragma unroll
    for (int mi = 0; mi < MI; ++mi) {
        #pragma unroll
        for (int ni = 0; ni < 4; ++ni) {
            const int col = col0 + wn + ni * 16 + lm;
            const float bv = bias ? bias[col] : 0.f;
            #pragma unroll
            for (int r = 0; r < 4; ++r) {
                const int row = row0 + wm + mi * 16 + q4 + r;
                if (row >= M) continue;
                float v = acc[mi][ni][r] + bv;
                if (relu) v = fmaxf(v, 0.f);
                const size_t idx = (size_t)row * N + col;
                if (Cf) Cf[idx] = v;
                if (C_hi) {
                    ushort h = f2bf(v);
                    C_hi[idx] = h;
                    if (C_lo) C_lo[idx] = f2bf(v - bf2f(h));
                }
            }
        }
    }
}

// ---------------------------------------------------------------------------
// Elementwise fp32 -> hi/lo bf16 split (vectorized x4)
__global__ __launch_bounds__(256) void split_kernel(
    const float* __restrict__ x, ushort* __restrict__ hi,
    ushort* __restrict__ lo, int n4)
{
    int i = blockIdx.x * 256 + threadIdx.x;
    if (i >= n4) return;
    float4 v = ((const float4*)x)[i];
    ushort h0, l0, h1, l1, h2, l2, h3, l3;
    split2(v.x, h0, l0); split2(v.y, h1, l1);
    split2(v.z, h2, l2); split2(v.w, h3, l3);
    ((ushort4*)hi)[i] = make_ushort4(h0, h1, h2, h3);
    ((ushort4*)lo)[i] = make_ushort4(l0, l1, l2, l3);
}

// ---------------------------------------------------------------------------
// W [K,N] fp32 -> WT hi/lo bf16 [N,K] (transpose + split; tiny matrices)
__global__ __launch_bounds__(256) void transpose_split_kernel(
    const float* __restrict__ W, ushort* __restrict__ Th,
    ushort* __restrict__ Tl, int K, int N)
{
    int i = blockIdx.x * 256 + threadIdx.x;
    if (i >= K * N) return;
    int k = i / N, n = i - k * N;
    ushort h, lo_;
    split2(W[i], h, lo_);
    Th[(size_t)n * K + k] = h;
    Tl[(size_t)n * K + k] = lo_;
}

// ---------------------------------------------------------------------------
// a_src[n,h] = dot(xp[n,h,:], att_src[h,:]); a_dst likewise. xp is bf16.
__global__ __launch_bounds__(256) void att_kernel(
    const ushort* __restrict__ xp, const float* __restrict__ att_src,
    const float* __restrict__ att_dst,
    float* __restrict__ a_src, float* __restrict__ a_dst, int n)
{
    int gw = (blockIdx.x * blockDim.x + threadIdx.x) >> 6;
    int lane = threadIdx.x & 63;
    if (gw >= 2 * n) return;
    int node = gw >> 1, h = gw & 1;
    const ushort* row = xp + (size_t)node * HC + h * OUT_C;
    const float* as = att_src + h * OUT_C;
    const float* ad = att_dst + h * OUT_C;
    float r0 = bfu(row[lane]), r1 = bfu(row[lane + 64]);
    float s1 = r0 * as[lane] + r1 * as[lane + 64];
    float s2 = r0 * ad[lane] + r1 * ad[lane + 64];
    #pragma unroll
    for (int off = 32; off > 0; off >>= 1) {
        s1 += __shfl_down(s1, off);
        s2 += __shfl_down(s2, off);
    }
    if (lane == 0) { a_src[gw] = s1; a_dst[gw] = s2; }
}

// ---------------------------------------------------------------------------
__global__ void zero_int2(int* deg, int* cursor, int n)
{
    int i = blockIdx.x * blockDim.x + threadIdx.x;
    if (i < n) { deg[i] = 0; cursor[i] = 0; }
}

__global__ __launch_bounds__(256) void hist_kernel(
    const int* __restrict__ dst, int* deg, int E_real, int ET)
{
    int e = blockIdx.x * blockDim.x + threadIdx.x;
    if (e >= ET) return;
    int d = (e < E_real) ? dst[e] : (e - E_real);
    atomicAdd(&deg[d], 1);
}

// Exclusive scan deg[0..n) -> rowptr[0..n]; single block, 256 threads.
// Middle scan parallelized (Hillis-Steele in LDS).
__global__ __launch_bounds__(256) void scan_kernel(
    const int* __restrict__ deg, int* __restrict__ rowptr, int n)
{
    __shared__ int part[256];
    const int t = threadIdx.x;
    const int chunk = (n + 255) / 256;
    const int lo = t * chunk;
    const int hi = min(lo + chunk, n);
    int s = 0;
    for (int i = lo; i < hi; ++i) s += deg[i];
    part[t] = s;
    __syncthreads();
    #pragma unroll
    for (int off = 1; off < 256; off <<= 1) {
        int add = (t >= off) ? part[t - off] : 0;
        __syncthreads();
        part[t] += add;
        __syncthreads();
    }
    int run = part[t] - s;   // exclusive prefix of this thread's chunk
    for (int i = lo; i < hi; ++i) { rowptr[i] = run; run += deg[i]; }
    if (t == 255) rowptr[n] = part[255];
}

__global__ __launch_bounds__(256) void scatter_kernel(
    const int* __restrict__ src, const int* __restrict__ dst,
    const int* __restrict__ rowptr, int* cursor,
    int* __restrict__ sorted_src, int E_real, int ET)
{
    int e = blockIdx.x * blockDim.x + threadIdx.x;
    if (e >= ET) return;
    int s, d;
    if (e < E_real) { s = src[e]; d = dst[e]; }
    else            { s = e - E_real; d = s; }
    int pos = rowptr[d] + atomicAdd(&cursor[d], 1);
    sorted_src[pos] = s;
}

// ---------------------------------------------------------------------------
// One WAVE per dst node; lane owns 4 channels; head = lane>>5. xp is bf16
// (ushort4 gather = 8 B/lane, 512 B coalesced per row). Emits xg split hi/lo.
__global__ __launch_bounds__(64) void gat_aggregate(
    const int* __restrict__ rowptr, const int* __restrict__ sorted_src,
    const float* __restrict__ a_src, const float* __restrict__ a_dst,
    const ushort* __restrict__ xp, const float* __restrict__ bias_g,
    ushort* __restrict__ xg_hi, ushort* __restrict__ xg_lo)
{
    __shared__ float s_w[2][64];
    __shared__ int   s_off[64];

    const int d = blockIdx.x;
    const int lane = threadIdx.x;
    const int h = lane >> 5;
    const int start = rowptr[d], end = rowptr[d + 1];

    const float ad0 = a_dst[2 * d + 0];
    const float ad1 = a_dst[2 * d + 1];

    float m0 = -FLT_MAX, m1 = -FLT_MAX;
    for (int e = start + lane; e < end; e += 64) {
        int s = sorted_src[e];
        float v0 = a_src[2 * s + 0] + ad0;
        float v1 = a_src[2 * s + 1] + ad1;
        v0 = (v0 > 0.f) ? v0 : NEG_SLOPE * v0;
        v1 = (v1 > 0.f) ? v1 : NEG_SLOPE * v1;
        m0 = fmaxf(m0, v0);
        m1 = fmaxf(m1, v1);
    }
    #pragma unroll
    for (int off = 32; off > 0; off >>= 1) {
        m0 = fmaxf(m0, __shfl_xor(m0, off));
        m1 = fmaxf(m1, __shfl_xor(m1, off));
    }

    float4 acc = make_float4(0.f, 0.f, 0.f, 0.f);
    float denom = 0.f;
    for (int e0 = start; e0 < end; e0 += 64) {
        int cnt = min(64, end - e0);
        if (lane < cnt) {
            int s = sorted_src[e0 + lane];
            float v0 = a_src[2 * s + 0] + ad0;
            float v1 = a_src[2 * s + 1] + ad1;
            v0 = (v0 > 0.f) ? v0 : NEG_SLOPE * v0;
            v1 = (v1 > 0.f) ? v1 : NEG_SLOPE * v1;
            s_w[0][lane] = expf(v0 - m0);
            s_w[1][lane] = expf(v1 - m1);
            s_off[lane] = s * HC;
        }
        __syncthreads();
        for (int j = 0; j < cnt; ++j) {
            float w = s_w[h][j];
            const ushort4 v = *(const ushort4*)(xp + s_off[j] + 4 * lane);
            denom += w;
            acc.x += w * bfu(v.x); acc.y += w * bfu(v.y);
            acc.z += w * bfu(v.z); acc.w += w * bfu(v.w);
        }
        __syncthreads();
    }

    float inv = 1.f / fmaxf(denom, 1e-16f);
    int c = 4 * lane;
    float4 bg = *(const float4*)(bias_g + c);
    float o0 = acc.x * inv + bg.x;
    float o1 = acc.y * inv + bg.y;
    float o2 = acc.z * inv + bg.z;
    float o3 = acc.w * inv + bg.w;
    ushort h0, l0, h1, l1, h2, l2, h3, l3;
    split2(o0, h0, l0); split2(o1, h1, l1);
    split2(o2, h2, l2); split2(o3, h3, l3);
    const size_t base = ((size_t)d * HC + c) >> 2;
    ((ushort4*)xg_hi)[base] = make_ushort4(h0, h1, h2, h3);
    ((ushort4*)xg_lo)[base] = make_ushort4(l0, l1, l2, l3);
}

// ---------------------------------------------------------------------------
extern "C" void kernel_launch(void* const* d_in, const int* in_sizes, int n_in,
                              void* d_out, int out_size, void* d_ws, size_t ws_size,
                              hipStream_t stream)
{
    const float* z       = (const float*)d_in[0];
    const int*   ei      = (const int*)d_in[1];    // [2,E] int32
    const float* W1      = (const float*)d_in[2];
    const float* b1      = (const float*)d_in[3];
    const float* W2      = (const float*)d_in[4];
    const float* b2      = (const float*)d_in[5];
    const float* Wg      = (const float*)d_in[6];
    const float* att_src = (const float*)d_in[7];
    const float* att_dst = (const float*)d_in[8];
    const float* bias_g  = (const float*)d_in[9];
    const float* W3      = (const float*)d_in[10];
    const float* b3      = (const float*)d_in[11];
    float* out = (float*)d_out;

    const int n = N_NODES;
    const int E_real = in_sizes[1] / 2;
    const int ET = E_real + n;
    const int* src = ei;
    const int* dst = ei + E_real;

    // Workspace layout. Aliases: z_hi/z_lo (dead after GEMM1) = x2_hi/x2_lo;
    // x1_hi/x1_lo (dead after GEMM2) = xg_hi/xg_lo.
    char* p = (char*)d_ws;
    auto alloc = [&](size_t bytes) {
        char* r = p;
        p += (bytes + 63) & ~(size_t)63;
        return r;
    };
    ushort* z_hi  = (ushort*)alloc((size_t)n * LATENT * 2);   // 20.48 MB
    ushort* z_lo  = (ushort*)alloc((size_t)n * LATENT * 2);
    ushort* x1_hi = (ushort*)alloc((size_t)n * HID * 2);      // 10.24 MB
    ushort* x1_lo = (ushort*)alloc((size_t)n * HID * 2);
    ushort* xp_bf = (ushort*)alloc((size_t)n * HC * 2);       // 10.24 MB (bf16!)
    ushort* W1T_h = (ushort*)alloc((size_t)LATENT * HID * 2);
    ushort* W1T_l = (ushort*)alloc((size_t)LATENT * HID * 2);
    ushort* W2T_h = (ushort*)alloc((size_t)HID * 512 * 2);
    ushort* W2T_l = (ushort*)alloc((size_t)HID * 512 * 2);
    ushort* WgT_h = (ushort*)alloc((size_t)512 * HC * 2);
    ushort* WgT_l = (ushort*)alloc((size_t)512 * HC * 2);
    ushort* W3T_h = (ushort*)alloc((size_t)HC * 512 * 2);
    ushort* W3T_l = (ushort*)alloc((size_t)HC * 512 * 2);
    float* a_src = (float*)alloc((size_t)2 * n * 4);
    float* a_dst = (float*)alloc((size_t)2 * n * 4);
    int* deg        = (int*)alloc((size_t)n * 4);
    int* rowptr     = (int*)alloc(((size_t)n + 1) * 4);
    int* cursor     = (int*)alloc((size_t)n * 4);
    int* sorted_src = (int*)alloc((size_t)ET * 4);
    ushort* x2_hi = z_hi;    // reuse
    ushort* x2_lo = z_lo;
    ushort* xg_hi = x1_hi;   // reuse
    ushort* xg_lo = x1_lo;

    const int gm64  = (n + 63) / 64;     // 313
    const int gm128 = (n + 127) / 128;   // 157

    // input/weight splits
    split_kernel<<<(n * LATENT / 4 + 255) / 256, 256, 0, stream>>>(
        z, z_hi, z_lo, n * LATENT / 4);
    transpose_split_kernel<<<(LATENT * HID + 255) / 256, 256, 0, stream>>>(
        W1, W1T_h, W1T_l, LATENT, HID);
    transpose_split_kernel<<<(HID * 512 + 255) / 256, 256, 0, stream>>>(
        W2, W2T_h, W2T_l, HID, 512);
    transpose_split_kernel<<<(512 * HC + 255) / 256, 256, 0, stream>>>(
        Wg, WgT_h, WgT_l, 512, HC);
    transpose_split_kernel<<<(HC * 512 + 255) / 256, 256, 0, stream>>>(
        W3, W3T_h, W3T_l, HC, 512);

    // GEMM1: x1 = relu(z @ W1 + b1)   [20000,512]x[512,256] -> split (BM=64)
    gemm_split_mfma<64><<<dim3(gm64, HID / 128), 256, 0, stream>>>(
        z_hi, z_lo, W1T_h, W1T_l, b1, nullptr, x1_hi, x1_lo, n, HID, LATENT, 1);
    // GEMM2: x2 = relu(x1 @ W2 + b2)  [20000,256]x[256,512] -> split (BM=128)
    gemm_split_mfma<128><<<dim3(gm128, 512 / 128), 256, 0, stream>>>(
        x1_hi, x1_lo, W2T_h, W2T_l, b2, nullptr, x2_hi, x2_lo, n, 512, HID, 1);
    // GEMM3: xp = x2 @ Wg             [20000,512]x[512,256] -> bf16 (BM=64)
    gemm_split_mfma<64><<<dim3(gm64, HC / 128), 256, 0, stream>>>(
        x2_hi, x2_lo, WgT_h, WgT_l, nullptr, nullptr, xp_bf, nullptr, n, HC, 512, 0);

    // attention logits (bf16 xp)
    att_kernel<<<(2 * n + 3) / 4, 256, 0, stream>>>(
        xp_bf, att_src, att_dst, a_src, a_dst, n);
    // CSR build
    zero_int2<<<(n + 255) / 256, 256, 0, stream>>>(deg, cursor, n);
    hist_kernel<<<(ET + 255) / 256, 256, 0, stream>>>(dst, deg, E_real, ET);
    scan_kernel<<<1, 256, 0, stream>>>(deg, rowptr, n);
    scatter_kernel<<<(ET + 255) / 256, 256, 0, stream>>>(
        src, dst, rowptr, cursor, sorted_src, E_real, ET);
    // softmax + aggregate -> xg (split)
    gat_aggregate<<<n, 64, 0, stream>>>(
        rowptr, sorted_src, a_src, a_dst, xp_bf, bias_g, xg_hi, xg_lo);

    // GEMM4: out = xg @ W3 + b3       [20000,256]x[256,512] -> fp32 (BM=128)
    gemm_split_mfma<128><<<dim3(gm128, 512 / 128), 256, 0, stream>>>(
        xg_hi, xg_lo, W3T_h, W3T_l, b3, out, nullptr, nullptr, n, 512, HC, 0);
}

// Round 8
// 440.501 us; speedup vs baseline: 1.3172x; 1.3172x over previous
//
#include <hip/hip_runtime.h>
#include <hip/hip_bf16.h>
#include <float.h>

// Problem constants (from reference)
#define N_NODES 20000
#define LATENT  512
#define HID     256
#define OUT_C   128
#define HEADS   2
#define HC      256   // HEADS*OUT_C
#define NEG_SLOPE 0.2f

typedef __attribute__((ext_vector_type(8))) short short8;  // 8 bf16 = 4 VGPRs
typedef __attribute__((ext_vector_type(4))) float f32x4;

// ---------------------------------------------------------------------------
__device__ __forceinline__ ushort f2bf(float v) {
    __hip_bfloat16 h = __float2bfloat16(v);
    return *(ushort*)&h;
}
__device__ __forceinline__ float bf2f(ushort u) {
    __hip_bfloat16 h = *(__hip_bfloat16*)&u;
    return __bfloat162float(h);
}
__device__ __forceinline__ float bfu(ushort u) {   // exact bf16 -> fp32
    return __uint_as_float((unsigned)u << 16);
}
__device__ __forceinline__ void split2(float v, ushort& hi, ushort& lo) {
    hi = f2bf(v);
    lo = f2bf(v - bf2f(hi));
}

// async global->LDS DMA, 16B per lane. LDS dest is WAVE-UNIFORM base +
// lane*16 (m104/m108); per-lane scatter impossible -> XOR swizzle instead.
__device__ __forceinline__ void gl_lds16(const ushort* g, ushort* l) {
    __builtin_amdgcn_global_load_lds(
        (const __attribute__((address_space(1))) unsigned int*)g,
        (__attribute__((address_space(3))) unsigned int*)l, 16, 0, 0);
}

// ---------------------------------------------------------------------------
// Split-bf16 MFMA GEMM:  C = act( Ah*Bh + Ah*Bl + Al*Bh + bias )
// A [M,K] hi/lo bf16 row-major (M-side arrays over-allocated by 128 rows so
// OOB tile rows read garbage, never fault; garbage stays in C-rows >= M
// which are not stored). B TRANSPOSED: BT [N,K] hi/lo bf16, N % 128 == 0.
// Block tile 128x128, 4 waves (64x64 each, 4x4 frags), BK=32.
// Staging: global_load_lds width=16, no VGPR prefetch (R5's 8x int4 prefetch
// spilled 128B/thread/iter -> 203MB scratch writes). LDS unpadded 32 shorts/row
// with 16B-chunk XOR swizzle: chunk(r,c) stored at slot c^(r&3). ds_read
// pattern ~2 lanes/bank-group -> cheap (m136).
__global__ __launch_bounds__(256) void gemm_split_mfma(
    const ushort* __restrict__ A_hi, const ushort* __restrict__ A_lo,
    const ushort* __restrict__ BT_hi, const ushort* __restrict__ BT_lo,
    const float* __restrict__ bias,
    float* __restrict__ Cf, ushort* __restrict__ C_hi, ushort* __restrict__ C_lo,
    int M, int N, int K, int relu)
{
    __shared__ ushort lds[4 * 128 * 32];   // Ah, Al, Bh, Bl: 32 KB total
    ushort* ldsAh = lds;
    ushort* ldsAl = lds + 128 * 32;
    ushort* ldsBh = lds + 2 * 128 * 32;
    ushort* ldsBl = lds + 3 * 128 * 32;

    const int t = threadIdx.x;
    const int l = t & 63;
    const int w = t >> 6;
    const int wm = (w >> 1) * 64;          // wave M offset in tile
    const int wn = (w & 1) * 64;           // wave N offset in tile
    const int lm = l & 15;
    const int q  = l >> 4;                 // k-chunk id (0..3)
    const int q4 = q * 4;                  // C frag row offset

    const int row0 = blockIdx.x * 128;
    const int col0 = blockIdx.y * 128;

    // Staging geometry: instruction (j,w) covers LDS chunks (j*4+w)*64..+64,
    // i.e. rows (j*4+w)*16..+16. Lane l -> row +=(l>>2), slot c=l&3; the
    // global chunk it must fetch is c ^ (row&3) = (l&3)^((l>>2)&3).
    const int jr0 = w * 16 + (l >> 2);                   // rows for j=0 (j=1: +64)
    const int gsh = (((l & 3) ^ ((l >> 2) & 3)) << 3);   // global offset, shorts
    const ushort* gA0h = A_hi + (size_t)(row0 + jr0) * K + gsh;
    const ushort* gA1h = gA0h + (size_t)64 * K;
    const ushort* gA0l = A_lo + (size_t)(row0 + jr0) * K + gsh;
    const ushort* gA1l = gA0l + (size_t)64 * K;
    const ushort* gB0h = BT_hi + (size_t)(col0 + jr0) * K + gsh;
    const ushort* gB1h = gB0h + (size_t)64 * K;
    const ushort* gB0l = BT_lo + (size_t)(col0 + jr0) * K + gsh;
    const ushort* gB1l = gB0l + (size_t)64 * K;
    // wave-uniform LDS dests (shorts): (j*4+w)*64 chunks * 8 shorts
    ushort* dA0h = ldsAh + w * 512;  ushort* dA1h = ldsAh + (4 + w) * 512;
    ushort* dA0l = ldsAl + w * 512;  ushort* dA1l = ldsAl + (4 + w) * 512;
    ushort* dB0h = ldsBh + w * 512;  ushort* dB1h = ldsBh + (4 + w) * 512;
    ushort* dB0l = ldsBl + w * 512;  ushort* dB1l = ldsBl + (4 + w) * 512;

    // fragment-read swizzle: row ar -> slot (q ^ (ar&3)); ar&3 == lm&3
    const int csw = ((q ^ (lm & 3)) << 3);

    const f32x4 zf = {0.f, 0.f, 0.f, 0.f};
    f32x4 acc[4][4];
    #pragma unroll
    for (int i = 0; i < 4; ++i)
        #pragma unroll
        for (int j = 0; j < 4; ++j) acc[i][j] = zf;

    for (int k0 = 0; k0 < K; k0 += 32) {
        __syncthreads();   // previous iteration's frag reads done
        gl_lds16(gA0h + k0, dA0h);
        gl_lds16(gA1h + k0, dA1h);
        gl_lds16(gA0l + k0, dA0l);
        gl_lds16(gA1l + k0, dA1l);
        gl_lds16(gB0h + k0, dB0h);
        gl_lds16(gB1h + k0, dB1h);
        gl_lds16(gB0l + k0, dB0l);
        gl_lds16(gB1l + k0, dB1l);
        __syncthreads();   // barrier drains vmcnt -> LDS tiles ready

        short8 bh[4], bl[4];
        #pragma unroll
        for (int ni = 0; ni < 4; ++ni) {
            const int boff = (wn + ni * 16 + lm) * 32 + csw;
            bh[ni] = *(const short8*)&ldsBh[boff];
            bl[ni] = *(const short8*)&ldsBl[boff];
        }
        #pragma unroll
        for (int mi = 0; mi < 4; ++mi) {
            const int aoff = (wm + mi * 16 + lm) * 32 + csw;
            short8 ah = *(const short8*)&ldsAh[aoff];
            short8 al = *(const short8*)&ldsAl[aoff];
            #pragma unroll
            for (int ni = 0; ni < 4; ++ni) {
                acc[mi][ni] = __builtin_amdgcn_mfma_f32_16x16x32_bf16(ah, bh[ni], acc[mi][ni], 0, 0, 0);
                acc[mi][ni] = __builtin_amdgcn_mfma_f32_16x16x32_bf16(ah, bl[ni], acc[mi][ni], 0, 0, 0);
                acc[mi][ni] = __builtin_amdgcn_mfma_f32_16x16x32_bf16(al, bh[ni], acc[mi][ni], 0, 0, 0);
            }
        }
    }

    // Epilogue. C/D frag: col = lane&15, row = (lane>>4)*4 + reg  [m89/m91]
    #pragma unroll
    for (int mi = 0; mi < 4; ++mi) {
        #pragma unroll
        for (int ni = 0; ni < 4; ++ni) {
            const int col = col0 + wn + ni * 16 + lm;
            const float bv = bias ? bias[col] : 0.f;
            #pragma unroll
            for (int r = 0; r < 4; ++r) {
                const int row = row0 + wm + mi * 16 + q4 + r;
                if (row >= M) continue;
                float v = acc[mi][ni][r] + bv;
                if (relu) v = fmaxf(v, 0.f);
                const size_t idx = (size_t)row * N + col;
                if (Cf) Cf[idx] = v;
                if (C_hi) {
                    ushort h = f2bf(v);
                    C_hi[idx] = h;
                    if (C_lo) C_lo[idx] = f2bf(v - bf2f(h));
                }
            }
        }
    }
}

// ---------------------------------------------------------------------------
// Elementwise fp32 -> hi/lo bf16 split (vectorized x4)
__global__ __launch_bounds__(256) void split_kernel(
    const float* __restrict__ x, ushort* __restrict__ hi,
    ushort* __restrict__ lo, int n4)
{
    int i = blockIdx.x * 256 + threadIdx.x;
    if (i >= n4) return;
    float4 v = ((const float4*)x)[i];
    ushort h0, l0, h1, l1, h2, l2, h3, l3;
    split2(v.x, h0, l0); split2(v.y, h1, l1);
    split2(v.z, h2, l2); split2(v.w, h3, l3);
    ((ushort4*)hi)[i] = make_ushort4(h0, h1, h2, h3);
    ((ushort4*)lo)[i] = make_ushort4(l0, l1, l2, l3);
}

// ---------------------------------------------------------------------------
// W [K,N] fp32 -> WT hi/lo bf16 [N,K] (transpose + split; tiny matrices)
__global__ __launch_bounds__(256) void transpose_split_kernel(
    const float* __restrict__ W, ushort* __restrict__ Th,
    ushort* __restrict__ Tl, int K, int N)
{
    int i = blockIdx.x * 256 + threadIdx.x;
    if (i >= K * N) return;
    int k = i / N, n = i - k * N;
    ushort h, lo_;
    split2(W[i], h, lo_);
    Th[(size_t)n * K + k] = h;
    Tl[(size_t)n * K + k] = lo_;
}

// ---------------------------------------------------------------------------
// a_src[n,h] = dot(xp[n,h,:], att_src[h,:]); a_dst likewise. xp is bf16.
__global__ __launch_bounds__(256) void att_kernel(
    const ushort* __restrict__ xp, const float* __restrict__ att_src,
    const float* __restrict__ att_dst,
    float* __restrict__ a_src, float* __restrict__ a_dst, int n)
{
    int gw = (blockIdx.x * blockDim.x + threadIdx.x) >> 6;
    int lane = threadIdx.x & 63;
    if (gw >= 2 * n) return;
    int node = gw >> 1, h = gw & 1;
    const ushort* row = xp + (size_t)node * HC + h * OUT_C;
    const float* as = att_src + h * OUT_C;
    const float* ad = att_dst + h * OUT_C;
    float r0 = bfu(row[lane]), r1 = bfu(row[lane + 64]);
    float s1 = r0 * as[lane] + r1 * as[lane + 64];
    float s2 = r0 * ad[lane] + r1 * ad[lane + 64];
    #pragma unroll
    for (int off = 32; off > 0; off >>= 1) {
        s1 += __shfl_down(s1, off);
        s2 += __shfl_down(s2, off);
    }
    if (lane == 0) { a_src[gw] = s1; a_dst[gw] = s2; }
}

// ---------------------------------------------------------------------------
__global__ void zero_int2(int* deg, int* cursor, int n)
{
    int i = blockIdx.x * blockDim.x + threadIdx.x;
    if (i < n) { deg[i] = 0; cursor[i] = 0; }
}

__global__ __launch_bounds__(256) void hist_kernel(
    const int* __restrict__ dst, int* deg, int E_real, int ET)
{
    int e = blockIdx.x * blockDim.x + threadIdx.x;
    if (e >= ET) return;
    int d = (e < E_real) ? dst[e] : (e - E_real);
    atomicAdd(&deg[d], 1);
}

// Exclusive scan deg[0..n) -> rowptr[0..n]; single block, 256 threads.
__global__ __launch_bounds__(256) void scan_kernel(
    const int* __restrict__ deg, int* __restrict__ rowptr, int n)
{
    __shared__ int part[256];
    const int t = threadIdx.x;
    const int chunk = (n + 255) / 256;
    const int lo = t * chunk;
    const int hi = min(lo + chunk, n);
    int s = 0;
    for (int i = lo; i < hi; ++i) s += deg[i];
    part[t] = s;
    __syncthreads();
    #pragma unroll
    for (int off = 1; off < 256; off <<= 1) {
        int add = (t >= off) ? part[t - off] : 0;
        __syncthreads();
        part[t] += add;
        __syncthreads();
    }
    int run = part[t] - s;   // exclusive prefix of this thread's chunk
    for (int i = lo; i < hi; ++i) { rowptr[i] = run; run += deg[i]; }
    if (t == 255) rowptr[n] = part[255];
}

__global__ __launch_bounds__(256) void scatter_kernel(
    const int* __restrict__ src, const int* __restrict__ dst,
    const int* __restrict__ rowptr, int* cursor,
    int* __restrict__ sorted_src, int E_real, int ET)
{
    int e = blockIdx.x * blockDim.x + threadIdx.x;
    if (e >= ET) return;
    int s, d;
    if (e < E_real) { s = src[e]; d = dst[e]; }
    else            { s = e - E_real; d = s; }
    int pos = rowptr[d] + atomicAdd(&cursor[d], 1);
    sorted_src[pos] = s;
}

// ---------------------------------------------------------------------------
// One WAVE per dst node; lane owns 4 channels; head = lane>>5. xp is bf16
// (ushort4 gather = 8 B/lane, 512 B coalesced per row). Emits xg split hi/lo.
__global__ __launch_bounds__(64) void gat_aggregate(
    const int* __restrict__ rowptr, const int* __restrict__ sorted_src,
    const float* __restrict__ a_src, const float* __restrict__ a_dst,
    const ushort* __restrict__ xp, const float* __restrict__ bias_g,
    ushort* __restrict__ xg_hi, ushort* __restrict__ xg_lo)
{
    __shared__ float s_w[2][64];
    __shared__ int   s_off[64];

    const int d = blockIdx.x;
    const int lane = threadIdx.x;
    const int h = lane >> 5;
    const int start = rowptr[d], end = rowptr[d + 1];

    const float ad0 = a_dst[2 * d + 0];
    const float ad1 = a_dst[2 * d + 1];

    float m0 = -FLT_MAX, m1 = -FLT_MAX;
    for (int e = start + lane; e < end; e += 64) {
        int s = sorted_src[e];
        float v0 = a_src[2 * s + 0] + ad0;
        float v1 = a_src[2 * s + 1] + ad1;
        v0 = (v0 > 0.f) ? v0 : NEG_SLOPE * v0;
        v1 = (v1 > 0.f) ? v1 : NEG_SLOPE * v1;
        m0 = fmaxf(m0, v0);
        m1 = fmaxf(m1, v1);
    }
    #pragma unroll
    for (int off = 32; off > 0; off >>= 1) {
        m0 = fmaxf(m0, __shfl_xor(m0, off));
        m1 = fmaxf(m1, __shfl_xor(m1, off));
    }

    float4 acc = make_float4(0.f, 0.f, 0.f, 0.f);
    float denom = 0.f;
    for (int e0 = start; e0 < end; e0 += 64) {
        int cnt = min(64, end - e0);
        if (lane < cnt) {
            int s = sorted_src[e0 + lane];
            float v0 = a_src[2 * s + 0] + ad0;
            float v1 = a_src[2 * s + 1] + ad1;
            v0 = (v0 > 0.f) ? v0 : NEG_SLOPE * v0;
            v1 = (v1 > 0.f) ? v1 : NEG_SLOPE * v1;
            s_w[0][lane] = expf(v0 - m0);
            s_w[1][lane] = expf(v1 - m1);
            s_off[lane] = s * HC;
        }
        __syncthreads();
        for (int j = 0; j < cnt; ++j) {
            float w = s_w[h][j];
            const ushort4 v = *(const ushort4*)(xp + s_off[j] + 4 * lane);
            denom += w;
            acc.x += w * bfu(v.x); acc.y += w * bfu(v.y);
            acc.z += w * bfu(v.z); acc.w += w * bfu(v.w);
        }
        __syncthreads();
    }

    float inv = 1.f / fmaxf(denom, 1e-16f);
    int c = 4 * lane;
    float4 bg = *(const float4*)(bias_g + c);
    float o0 = acc.x * inv + bg.x;
    float o1 = acc.y * inv + bg.y;
    float o2 = acc.z * inv + bg.z;
    float o3 = acc.w * inv + bg.w;
    ushort h0, l0, h1, l1, h2, l2, h3, l3;
    split2(o0, h0, l0); split2(o1, h1, l1);
    split2(o2, h2, l2); split2(o3, h3, l3);
    const size_t base = ((size_t)d * HC + c) >> 2;
    ((ushort4*)xg_hi)[base] = make_ushort4(h0, h1, h2, h3);
    ((ushort4*)xg_lo)[base] = make_ushort4(l0, l1, l2, l3);
}

// ---------------------------------------------------------------------------
extern "C" void kernel_launch(void* const* d_in, const int* in_sizes, int n_in,
                              void* d_out, int out_size, void* d_ws, size_t ws_size,
                              hipStream_t stream)
{
    const float* z       = (const float*)d_in[0];
    const int*   ei      = (const int*)d_in[1];    // [2,E] int32
    const float* W1      = (const float*)d_in[2];
    const float* b1      = (const float*)d_in[3];
    const float* W2      = (const float*)d_in[4];
    const float* b2      = (const float*)d_in[5];
    const float* Wg      = (const float*)d_in[6];
    const float* att_src = (const float*)d_in[7];
    const float* att_dst = (const float*)d_in[8];
    const float* bias_g  = (const float*)d_in[9];
    const float* W3      = (const float*)d_in[10];
    const float* b3      = (const float*)d_in[11];
    float* out = (float*)d_out;

    const int n = N_NODES;
    const int E_real = in_sizes[1] / 2;
    const int ET = E_real + n;
    const int* src = ei;
    const int* dst = ei + E_real;

    // Workspace layout. M-side (GEMM A) arrays over-allocated by 128 rows so
    // global_load_lds staging of the last (partial) tile never faults.
    // Aliases: z_hi/z_lo (dead after GEMM1) = x2_hi/x2_lo; x1 = xg.
    char* p = (char*)d_ws;
    auto alloc = [&](size_t bytes) {
        char* r = p;
        p += (bytes + 63) & ~(size_t)63;
        return r;
    };
    const int np = n + 128;   // padded row count
    ushort* z_hi  = (ushort*)alloc((size_t)np * LATENT * 2);
    ushort* z_lo  = (ushort*)alloc((size_t)np * LATENT * 2);
    ushort* x1_hi = (ushort*)alloc((size_t)np * HID * 2);
    ushort* x1_lo = (ushort*)alloc((size_t)np * HID * 2);
    ushort* xp_bf = (ushort*)alloc((size_t)n * HC * 2);       // 10.24 MB bf16
    ushort* W1T_h = (ushort*)alloc((size_t)LATENT * HID * 2);
    ushort* W1T_l = (ushort*)alloc((size_t)LATENT * HID * 2);
    ushort* W2T_h = (ushort*)alloc((size_t)HID * 512 * 2);
    ushort* W2T_l = (ushort*)alloc((size_t)HID * 512 * 2);
    ushort* WgT_h = (ushort*)alloc((size_t)512 * HC * 2);
    ushort* WgT_l = (ushort*)alloc((size_t)512 * HC * 2);
    ushort* W3T_h = (ushort*)alloc((size_t)HC * 512 * 2);
    ushort* W3T_l = (ushort*)alloc((size_t)HC * 512 * 2);
    float* a_src = (float*)alloc((size_t)2 * n * 4);
    float* a_dst = (float*)alloc((size_t)2 * n * 4);
    int* deg        = (int*)alloc((size_t)n * 4);
    int* rowptr     = (int*)alloc(((size_t)n + 1) * 4);
    int* cursor     = (int*)alloc((size_t)n * 4);
    int* sorted_src = (int*)alloc((size_t)ET * 4);
    ushort* x2_hi = z_hi;    // reuse (row size 512 shorts, same as z)
    ushort* x2_lo = z_lo;
    ushort* xg_hi = x1_hi;   // reuse (row size 256 shorts, same as x1)
    ushort* xg_lo = x1_lo;

    const int gm128 = (n + 127) / 128;   // 157

    // input/weight splits
    split_kernel<<<(n * LATENT / 4 + 255) / 256, 256, 0, stream>>>(
        z, z_hi, z_lo, n * LATENT / 4);
    transpose_split_kernel<<<(LATENT * HID + 255) / 256, 256, 0, stream>>>(
        W1, W1T_h, W1T_l, LATENT, HID);
    transpose_split_kernel<<<(HID * 512 + 255) / 256, 256, 0, stream>>>(
        W2, W2T_h, W2T_l, HID, 512);
    transpose_split_kernel<<<(512 * HC + 255) / 256, 256, 0, stream>>>(
        Wg, WgT_h, WgT_l, 512, HC);
    transpose_split_kernel<<<(HC * 512 + 255) / 256, 256, 0, stream>>>(
        W3, W3T_h, W3T_l, HC, 512);

    // GEMM1: x1 = relu(z @ W1 + b1)   [20000,512]x[512,256] -> split
    gemm_split_mfma<<<dim3(gm128, HID / 128), 256, 0, stream>>>(
        z_hi, z_lo, W1T_h, W1T_l, b1, nullptr, x1_hi, x1_lo, n, HID, LATENT, 1);
    // GEMM2: x2 = relu(x1 @ W2 + b2)  [20000,256]x[256,512] -> split
    gemm_split_mfma<<<dim3(gm128, 512 / 128), 256, 0, stream>>>(
        x1_hi, x1_lo, W2T_h, W2T_l, b2, nullptr, x2_hi, x2_lo, n, 512, HID, 1);
    // GEMM3: xp = x2 @ Wg             [20000,512]x[512,256] -> bf16
    gemm_split_mfma<<<dim3(gm128, HC / 128), 256, 0, stream>>>(
        x2_hi, x2_lo, WgT_h, WgT_l, nullptr, nullptr, xp_bf, nullptr, n, HC, 512, 0);

    // attention logits (bf16 xp)
    att_kernel<<<(2 * n + 3) / 4, 256, 0, stream>>>(
        xp_bf, att_src, att_dst, a_src, a_dst, n);
    // CSR build
    zero_int2<<<(n + 255) / 256, 256, 0, stream>>>(deg, cursor, n);
    hist_kernel<<<(ET + 255) / 256, 256, 0, stream>>>(dst, deg, E_real, ET);
    scan_kernel<<<1, 256, 0, stream>>>(deg, rowptr, n);
    scatter_kernel<<<(ET + 255) / 256, 256, 0, stream>>>(
        src, dst, rowptr, cursor, sorted_src, E_real, ET);
    // softmax + aggregate -> xg (split)
    gat_aggregate<<<n, 64, 0, stream>>>(
        rowptr, sorted_src, a_src, a_dst, xp_bf, bias_g, xg_hi, xg_lo);

    // GEMM4: out = xg @ W3 + b3       [20000,256]x[256,512] -> fp32
    gemm_split_mfma<<<dim3(gm128, 512 / 128), 256, 0, stream>>>(
        xg_hi, xg_lo, W3T_h, W3T_l, b3, out, nullptr, nullptr, n, 512, HC, 0);
}

// Round 9
// 437.379 us; speedup vs baseline: 1.3266x; 1.0071x over previous
//
#include <hip/hip_runtime.h>
#include <hip/hip_bf16.h>
#include <float.h>

// Problem constants (from reference)
#define N_NODES 20000
#define LATENT  512
#define HID     256
#define OUT_C   128
#define HEADS   2
#define HC      256   // HEADS*OUT_C
#define NEG_SLOPE 0.2f

typedef __attribute__((ext_vector_type(8))) short short8;  // 8 bf16 = 4 VGPRs
typedef __attribute__((ext_vector_type(4))) float f32x4;

// ---------------------------------------------------------------------------
__device__ __forceinline__ ushort f2bf(float v) {
    __hip_bfloat16 h = __float2bfloat16(v);
    return *(ushort*)&h;
}
__device__ __forceinline__ float bf2f(ushort u) {
    __hip_bfloat16 h = *(__hip_bfloat16*)&u;
    return __bfloat162float(h);
}
__device__ __forceinline__ float bfu(ushort u) {   // exact bf16 -> fp32
    return __uint_as_float((unsigned)u << 16);
}
__device__ __forceinline__ void split2(float v, ushort& hi, ushort& lo) {
    hi = f2bf(v);
    lo = f2bf(v - bf2f(hi));
}

// async global->LDS DMA, 16B per lane. LDS dest is WAVE-UNIFORM base +
// lane*16 (m104/m108); per-lane scatter impossible -> XOR swizzle instead.
__device__ __forceinline__ void gl_lds16(const ushort* g, ushort* l) {
    __builtin_amdgcn_global_load_lds(
        (const __attribute__((address_space(1))) unsigned int*)g,
        (__attribute__((address_space(3))) unsigned int*)l, 16, 0, 0);
}

// ---------------------------------------------------------------------------
// Split-bf16 MFMA GEMM:  C = act( Ah*Bh + Ah*Bl + Al*Bh + bias )
// A [M,K] hi/lo bf16 row-major (M-side arrays over-allocated by 128 rows so
// OOB tile rows read garbage, never fault; garbage stays in C-rows >= M
// which are not stored). B TRANSPOSED: BT [N,K] hi/lo bf16, N % 128 == 0.
// Block tile 128x128, 4 waves (64x64 each, 4x4 frags), BK=32.
// R8: DOUBLE-BUFFERED K-loop (R7 issued DMAs then immediately drained at the
// barrier -> zero latency overlap -> MfmaUtil 8.9%): issue next tile's DMAs
// into the other 32KB buffer, compute current, one barrier/iter.
// Swizzle: 16B chunk c of row r stored at slot c^((r>>2)&3) -> frag reads are
// 2 lanes/bank-group (free, m136); R7's c^(r&3) was 4-way within quarters.
__global__ __launch_bounds__(256) void gemm_split_mfma(
    const ushort* __restrict__ A_hi, const ushort* __restrict__ A_lo,
    const ushort* __restrict__ BT_hi, const ushort* __restrict__ BT_lo,
    const float* __restrict__ bias,
    float* __restrict__ Cf, ushort* __restrict__ C_hi, ushort* __restrict__ C_lo,
    int M, int N, int K, int relu)
{
    // one buffer = {Ah, Al, Bh, Bl} tiles of 128x32 shorts = 16384 shorts (32KB)
    __shared__ ushort lds[2 * 16384];   // 64 KB total
    ushort* buf0 = lds;
    ushort* buf1 = lds + 16384;

    const int t = threadIdx.x;
    const int l = t & 63;
    const int w = t >> 6;
    const int wm = (w >> 1) * 64;          // wave M offset in tile
    const int wn = (w & 1) * 64;           // wave N offset in tile
    const int lm = l & 15;
    const int q  = l >> 4;                 // k-chunk id (0..3)
    const int q4 = q * 4;                  // C frag row offset

    const int row0 = blockIdx.x * 128;
    const int col0 = blockIdx.y * 128;

    // Staging geometry: instruction (j,w) covers LDS chunks (j*4+w)*64..+64,
    // i.e. rows (j*4+w)*16..+16. Lane l -> row += (l>>2), slot l&3; the
    // global chunk it must fetch is (l&3) ^ (((l>>2)>>2)&3) = (l&3)^((l>>4)&3).
    const int jr0 = w * 16 + (l >> 2);                   // rows for j=0 (j=1: +64)
    const int gsh = (((l & 3) ^ ((l >> 4) & 3)) << 3);   // global offset, shorts
    const ushort* gA0h = A_hi + (size_t)(row0 + jr0) * K + gsh;
    const ushort* gA1h = gA0h + (size_t)64 * K;
    const ushort* gA0l = A_lo + (size_t)(row0 + jr0) * K + gsh;
    const ushort* gA1l = gA0l + (size_t)64 * K;
    const ushort* gB0h = BT_hi + (size_t)(col0 + jr0) * K + gsh;
    const ushort* gB1h = gB0h + (size_t)64 * K;
    const ushort* gB0l = BT_lo + (size_t)(col0 + jr0) * K + gsh;
    const ushort* gB1l = gB0l + (size_t)64 * K;
    const int d0 = w * 512;          // wave-uniform LDS dest offset, j=0
    const int d1 = (4 + w) * 512;    // j=1

    // fragment-read swizzle: row X+lm (X mult of 16) -> slot q ^ ((lm>>2)&3)
    const int csw = ((q ^ ((lm >> 2) & 3)) << 3);

    const f32x4 zf = {0.f, 0.f, 0.f, 0.f};
    f32x4 acc[4][4];
    #pragma unroll
    for (int i = 0; i < 4; ++i)
        #pragma unroll
        for (int j = 0; j < 4; ++j) acc[i][j] = zf;

    auto issue = [&](int kk, ushort* B) {
        gl_lds16(gA0h + kk, B + d0);
        gl_lds16(gA1h + kk, B + d1);
        gl_lds16(gA0l + kk, B + 4096 + d0);
        gl_lds16(gA1l + kk, B + 4096 + d1);
        gl_lds16(gB0h + kk, B + 8192 + d0);
        gl_lds16(gB1h + kk, B + 8192 + d1);
        gl_lds16(gB0l + kk, B + 12288 + d0);
        gl_lds16(gB1l + kk, B + 12288 + d1);
    };

    auto compute = [&](const ushort* B) {
        short8 bh[4], bl[4];
        #pragma unroll
        for (int ni = 0; ni < 4; ++ni) {
            const int boff = (wn + ni * 16 + lm) * 32 + csw;
            bh[ni] = *(const short8*)&B[8192 + boff];
            bl[ni] = *(const short8*)&B[12288 + boff];
        }
        #pragma unroll
        for (int mi = 0; mi < 4; ++mi) {
            const int aoff = (wm + mi * 16 + lm) * 32 + csw;
            short8 ah = *(const short8*)&B[aoff];
            short8 al = *(const short8*)&B[4096 + aoff];
            #pragma unroll
            for (int ni = 0; ni < 4; ++ni) {
                acc[mi][ni] = __builtin_amdgcn_mfma_f32_16x16x32_bf16(ah, bh[ni], acc[mi][ni], 0, 0, 0);
                acc[mi][ni] = __builtin_amdgcn_mfma_f32_16x16x32_bf16(ah, bl[ni], acc[mi][ni], 0, 0, 0);
                acc[mi][ni] = __builtin_amdgcn_mfma_f32_16x16x32_bf16(al, bh[ni], acc[mi][ni], 0, 0, 0);
            }
        }
    };

    // Pipelined K-loop (K % 64 == 0): DMA for tile k+1 is in flight during
    // tile k's MFMAs; barrier at iteration end drains it "for free".
    issue(0, buf0);
    __syncthreads();
    for (int k0 = 0; k0 < K; k0 += 64) {
        issue(k0 + 32, buf1);
        compute(buf0);
        __syncthreads();
        if (k0 + 64 < K) issue(k0 + 64, buf0);
        compute(buf1);
        __syncthreads();
    }

    // Epilogue. C/D frag: col = lane&15, row = (lane>>4)*4 + reg  [m89/m91]
    #pragma unroll
    for (int mi = 0; mi < 4; ++mi) {
        #pragma unroll
        for (int ni = 0; ni < 4; ++ni) {
            const int col = col0 + wn + ni * 16 + lm;
            const float bv = bias ? bias[col] : 0.f;
            #pragma unroll
            for (int r = 0; r < 4; ++r) {
                const int row = row0 + wm + mi * 16 + q4 + r;
                if (row >= M) continue;
                float v = acc[mi][ni][r] + bv;
                if (relu) v = fmaxf(v, 0.f);
                const size_t idx = (size_t)row * N + col;
                if (Cf) Cf[idx] = v;
                if (C_hi) {
                    ushort h = f2bf(v);
                    C_hi[idx] = h;
                    if (C_lo) C_lo[idx] = f2bf(v - bf2f(h));
                }
            }
        }
    }
}

// ---------------------------------------------------------------------------
// Elementwise fp32 -> hi/lo bf16 split (vectorized x4)
__global__ __launch_bounds__(256) void split_kernel(
    const float* __restrict__ x, ushort* __restrict__ hi,
    ushort* __restrict__ lo, int n4)
{
    int i = blockIdx.x * 256 + threadIdx.x;
    if (i >= n4) return;
    float4 v = ((const float4*)x)[i];
    ushort h0, l0, h1, l1, h2, l2, h3, l3;
    split2(v.x, h0, l0); split2(v.y, h1, l1);
    split2(v.z, h2, l2); split2(v.w, h3, l3);
    ((ushort4*)hi)[i] = make_ushort4(h0, h1, h2, h3);
    ((ushort4*)lo)[i] = make_ushort4(l0, l1, l2, l3);
}

// ---------------------------------------------------------------------------
// W [K,N] fp32 -> WT hi/lo bf16 [N,K] (transpose + split; tiny matrices)
__global__ __launch_bounds__(256) void transpose_split_kernel(
    const float* __restrict__ W, ushort* __restrict__ Th,
    ushort* __restrict__ Tl, int K, int N)
{
    int i = blockIdx.x * 256 + threadIdx.x;
    if (i >= K * N) return;
    int k = i / N, n = i - k * N;
    ushort h, lo_;
    split2(W[i], h, lo_);
    Th[(size_t)n * K + k] = h;
    Tl[(size_t)n * K + k] = lo_;
}

// ---------------------------------------------------------------------------
// a_src[n,h] = dot(xp[n,h,:], att_src[h,:]); a_dst likewise. xp is bf16.
__global__ __launch_bounds__(256) void att_kernel(
    const ushort* __restrict__ xp, const float* __restrict__ att_src,
    const float* __restrict__ att_dst,
    float* __restrict__ a_src, float* __restrict__ a_dst, int n)
{
    int gw = (blockIdx.x * blockDim.x + threadIdx.x) >> 6;
    int lane = threadIdx.x & 63;
    if (gw >= 2 * n) return;
    int node = gw >> 1, h = gw & 1;
    const ushort* row = xp + (size_t)node * HC + h * OUT_C;
    const float* as = att_src + h * OUT_C;
    const float* ad = att_dst + h * OUT_C;
    float r0 = bfu(row[lane]), r1 = bfu(row[lane + 64]);
    float s1 = r0 * as[lane] + r1 * as[lane + 64];
    float s2 = r0 * ad[lane] + r1 * ad[lane + 64];
    #pragma unroll
    for (int off = 32; off > 0; off >>= 1) {
        s1 += __shfl_down(s1, off);
        s2 += __shfl_down(s2, off);
    }
    if (lane == 0) { a_src[gw] = s1; a_dst[gw] = s2; }
}

// ---------------------------------------------------------------------------
__global__ void zero_int2(int* deg, int* cursor, int n)
{
    int i = blockIdx.x * blockDim.x + threadIdx.x;
    if (i < n) { deg[i] = 0; cursor[i] = 0; }
}

__global__ __launch_bounds__(256) void hist_kernel(
    const int* __restrict__ dst, int* deg, int E_real, int ET)
{
    int e = blockIdx.x * blockDim.x + threadIdx.x;
    if (e >= ET) return;
    int d = (e < E_real) ? dst[e] : (e - E_real);
    atomicAdd(&deg[d], 1);
}

// Exclusive scan deg[0..n) -> rowptr[0..n]; single block, 256 threads.
__global__ __launch_bounds__(256) void scan_kernel(
    const int* __restrict__ deg, int* __restrict__ rowptr, int n)
{
    __shared__ int part[256];
    const int t = threadIdx.x;
    const int chunk = (n + 255) / 256;
    const int lo = t * chunk;
    const int hi = min(lo + chunk, n);
    int s = 0;
    for (int i = lo; i < hi; ++i) s += deg[i];
    part[t] = s;
    __syncthreads();
    #pragma unroll
    for (int off = 1; off < 256; off <<= 1) {
        int add = (t >= off) ? part[t - off] : 0;
        __syncthreads();
        part[t] += add;
        __syncthreads();
    }
    int run = part[t] - s;   // exclusive prefix of this thread's chunk
    for (int i = lo; i < hi; ++i) { rowptr[i] = run; run += deg[i]; }
    if (t == 255) rowptr[n] = part[255];
}

__global__ __launch_bounds__(256) void scatter_kernel(
    const int* __restrict__ src, const int* __restrict__ dst,
    const int* __restrict__ rowptr, int* cursor,
    int* __restrict__ sorted_src, int E_real, int ET)
{
    int e = blockIdx.x * blockDim.x + threadIdx.x;
    if (e >= ET) return;
    int s, d;
    if (e < E_real) { s = src[e]; d = dst[e]; }
    else            { s = e - E_real; d = s; }
    int pos = rowptr[d] + atomicAdd(&cursor[d], 1);
    sorted_src[pos] = s;
}

// ---------------------------------------------------------------------------
// One WAVE per dst node; lane owns 4 channels; head = lane>>5. xp is bf16
// (ushort4 gather = 8 B/lane, 512 B coalesced per row). Emits xg split hi/lo.
__global__ __launch_bounds__(64) void gat_aggregate(
    const int* __restrict__ rowptr, const int* __restrict__ sorted_src,
    const float* __restrict__ a_src, const float* __restrict__ a_dst,
    const ushort* __restrict__ xp, const float* __restrict__ bias_g,
    ushort* __restrict__ xg_hi, ushort* __restrict__ xg_lo)
{
    __shared__ float s_w[2][64];
    __shared__ int   s_off[64];

    const int d = blockIdx.x;
    const int lane = threadIdx.x;
    const int h = lane >> 5;
    const int start = rowptr[d], end = rowptr[d + 1];

    const float ad0 = a_dst[2 * d + 0];
    const float ad1 = a_dst[2 * d + 1];

    float m0 = -FLT_MAX, m1 = -FLT_MAX;
    for (int e = start + lane; e < end; e += 64) {
        int s = sorted_src[e];
        float v0 = a_src[2 * s + 0] + ad0;
        float v1 = a_src[2 * s + 1] + ad1;
        v0 = (v0 > 0.f) ? v0 : NEG_SLOPE * v0;
        v1 = (v1 > 0.f) ? v1 : NEG_SLOPE * v1;
        m0 = fmaxf(m0, v0);
        m1 = fmaxf(m1, v1);
    }
    #pragma unroll
    for (int off = 32; off > 0; off >>= 1) {
        m0 = fmaxf(m0, __shfl_xor(m0, off));
        m1 = fmaxf(m1, __shfl_xor(m1, off));
    }

    float4 acc = make_float4(0.f, 0.f, 0.f, 0.f);
    float denom = 0.f;
    for (int e0 = start; e0 < end; e0 += 64) {
        int cnt = min(64, end - e0);
        if (lane < cnt) {
            int s = sorted_src[e0 + lane];
            float v0 = a_src[2 * s + 0] + ad0;
            float v1 = a_src[2 * s + 1] + ad1;
            v0 = (v0 > 0.f) ? v0 : NEG_SLOPE * v0;
            v1 = (v1 > 0.f) ? v1 : NEG_SLOPE * v1;
            s_w[0][lane] = expf(v0 - m0);
            s_w[1][lane] = expf(v1 - m1);
            s_off[lane] = s * HC;
        }
        __syncthreads();
        for (int j = 0; j < cnt; ++j) {
            float w = s_w[h][j];
            const ushort4 v = *(const ushort4*)(xp + s_off[j] + 4 * lane);
            denom += w;
            acc.x += w * bfu(v.x); acc.y += w * bfu(v.y);
            acc.z += w * bfu(v.z); acc.w += w * bfu(v.w);
        }
        __syncthreads();
    }

    float inv = 1.f / fmaxf(denom, 1e-16f);
    int c = 4 * lane;
    float4 bg = *(const float4*)(bias_g + c);
    float o0 = acc.x * inv + bg.x;
    float o1 = acc.y * inv + bg.y;
    float o2 = acc.z * inv + bg.z;
    float o3 = acc.w * inv + bg.w;
    ushort h0, l0, h1, l1, h2, l2, h3, l3;
    split2(o0, h0, l0); split2(o1, h1, l1);
    split2(o2, h2, l2); split2(o3, h3, l3);
    const size_t base = ((size_t)d * HC + c) >> 2;
    ((ushort4*)xg_hi)[base] = make_ushort4(h0, h1, h2, h3);
    ((ushort4*)xg_lo)[base] = make_ushort4(l0, l1, l2, l3);
}

// ---------------------------------------------------------------------------
extern "C" void kernel_launch(void* const* d_in, const int* in_sizes, int n_in,
                              void* d_out, int out_size, void* d_ws, size_t ws_size,
                              hipStream_t stream)
{
    const float* z       = (const float*)d_in[0];
    const int*   ei      = (const int*)d_in[1];    // [2,E] int32
    const float* W1      = (const float*)d_in[2];
    const float* b1      = (const float*)d_in[3];
    const float* W2      = (const float*)d_in[4];
    const float* b2      = (const float*)d_in[5];
    const float* Wg      = (const float*)d_in[6];
    const float* att_src = (const float*)d_in[7];
    const float* att_dst = (const float*)d_in[8];
    const float* bias_g  = (const float*)d_in[9];
    const float* W3      = (const float*)d_in[10];
    const float* b3      = (const float*)d_in[11];
    float* out = (float*)d_out;

    const int n = N_NODES;
    const int E_real = in_sizes[1] / 2;
    const int ET = E_real + n;
    const int* src = ei;
    const int* dst = ei + E_real;

    // Workspace layout. M-side (GEMM A) arrays over-allocated by 128 rows so
    // global_load_lds staging of the last (partial) tile never faults.
    // Aliases: z_hi/z_lo (dead after GEMM1) = x2_hi/x2_lo; x1 = xg.
    char* p = (char*)d_ws;
    auto alloc = [&](size_t bytes) {
        char* r = p;
        p += (bytes + 63) & ~(size_t)63;
        return r;
    };
    const int np = n + 128;   // padded row count
    ushort* z_hi  = (ushort*)alloc((size_t)np * LATENT * 2);
    ushort* z_lo  = (ushort*)alloc((size_t)np * LATENT * 2);
    ushort* x1_hi = (ushort*)alloc((size_t)np * HID * 2);
    ushort* x1_lo = (ushort*)alloc((size_t)np * HID * 2);
    ushort* xp_bf = (ushort*)alloc((size_t)n * HC * 2);       // 10.24 MB bf16
    ushort* W1T_h = (ushort*)alloc((size_t)LATENT * HID * 2);
    ushort* W1T_l = (ushort*)alloc((size_t)LATENT * HID * 2);
    ushort* W2T_h = (ushort*)alloc((size_t)HID * 512 * 2);
    ushort* W2T_l = (ushort*)alloc((size_t)HID * 512 * 2);
    ushort* WgT_h = (ushort*)alloc((size_t)512 * HC * 2);
    ushort* WgT_l = (ushort*)alloc((size_t)512 * HC * 2);
    ushort* W3T_h = (ushort*)alloc((size_t)HC * 512 * 2);
    ushort* W3T_l = (ushort*)alloc((size_t)HC * 512 * 2);
    float* a_src = (float*)alloc((size_t)2 * n * 4);
    float* a_dst = (float*)alloc((size_t)2 * n * 4);
    int* deg        = (int*)alloc((size_t)n * 4);
    int* rowptr     = (int*)alloc(((size_t)n + 1) * 4);
    int* cursor     = (int*)alloc((size_t)n * 4);
    int* sorted_src = (int*)alloc((size_t)ET * 4);
    ushort* x2_hi = z_hi;    // reuse (row size 512 shorts, same as z)
    ushort* x2_lo = z_lo;
    ushort* xg_hi = x1_hi;   // reuse (row size 256 shorts, same as x1)
    ushort* xg_lo = x1_lo;

    const int gm128 = (n + 127) / 128;   // 157

    // input/weight splits
    split_kernel<<<(n * LATENT / 4 + 255) / 256, 256, 0, stream>>>(
        z, z_hi, z_lo, n * LATENT / 4);
    transpose_split_kernel<<<(LATENT * HID + 255) / 256, 256, 0, stream>>>(
        W1, W1T_h, W1T_l, LATENT, HID);
    transpose_split_kernel<<<(HID * 512 + 255) / 256, 256, 0, stream>>>(
        W2, W2T_h, W2T_l, HID, 512);
    transpose_split_kernel<<<(512 * HC + 255) / 256, 256, 0, stream>>>(
        Wg, WgT_h, WgT_l, 512, HC);
    transpose_split_kernel<<<(HC * 512 + 255) / 256, 256, 0, stream>>>(
        W3, W3T_h, W3T_l, HC, 512);

    // GEMM1: x1 = relu(z @ W1 + b1)   [20000,512]x[512,256] -> split
    gemm_split_mfma<<<dim3(gm128, HID / 128), 256, 0, stream>>>(
        z_hi, z_lo, W1T_h, W1T_l, b1, nullptr, x1_hi, x1_lo, n, HID, LATENT, 1);
    // GEMM2: x2 = relu(x1 @ W2 + b2)  [20000,256]x[256,512] -> split
    gemm_split_mfma<<<dim3(gm128, 512 / 128), 256, 0, stream>>>(
        x1_hi, x1_lo, W2T_h, W2T_l, b2, nullptr, x2_hi, x2_lo, n, 512, HID, 1);
    // GEMM3: xp = x2 @ Wg             [20000,512]x[512,256] -> bf16
    gemm_split_mfma<<<dim3(gm128, HC / 128), 256, 0, stream>>>(
        x2_hi, x2_lo, WgT_h, WgT_l, nullptr, nullptr, xp_bf, nullptr, n, HC, 512, 0);

    // attention logits (bf16 xp)
    att_kernel<<<(2 * n + 3) / 4, 256, 0, stream>>>(
        xp_bf, att_src, att_dst, a_src, a_dst, n);
    // CSR build
    zero_int2<<<(n + 255) / 256, 256, 0, stream>>>(deg, cursor, n);
    hist_kernel<<<(ET + 255) / 256, 256, 0, stream>>>(dst, deg, E_real, ET);
    scan_kernel<<<1, 256, 0, stream>>>(deg, rowptr, n);
    scatter_kernel<<<(ET + 255) / 256, 256, 0, stream>>>(
        src, dst, rowptr, cursor, sorted_src, E_real, ET);
    // softmax + aggregate -> xg (split)
    gat_aggregate<<<n, 64, 0, stream>>>(
        rowptr, sorted_src, a_src, a_dst, xp_bf, bias_g, xg_hi, xg_lo);

    // GEMM4: out = xg @ W3 + b3       [20000,256]x[256,512] -> fp32
    gemm_split_mfma<<<dim3(gm128, 512 / 128), 256, 0, stream>>>(
        xg_hi, xg_lo, W3T_h, W3T_l, b3, out, nullptr, nullptr, n, 512, HC, 0);
}

// Round 10
// 350.861 us; speedup vs baseline: 1.6537x; 1.2466x over previous
//
#include <hip/hip_runtime.h>
#include <hip/hip_bf16.h>
#include <float.h>

// Problem constants (from reference)
#define N_NODES 20000
#define LATENT  512
#define HID     256
#define OUT_C   128
#define HEADS   2
#define HC      256   // HEADS*OUT_C
#define NEG_SLOPE 0.2f

typedef _Float16 half8 __attribute__((ext_vector_type(8)));  // 8 f16 = 4 VGPRs
typedef __attribute__((ext_vector_type(4))) float f32x4;

// ---------------------------------------------------------------------------
__device__ __forceinline__ ushort f2h(float v) {
    _Float16 h = (_Float16)v;
    return *(ushort*)&h;
}
__device__ __forceinline__ float h2f(ushort u) {
    _Float16 h = *(_Float16*)&u;
    return (float)h;
}

// async global->LDS DMA, 16B per lane. LDS dest is WAVE-UNIFORM base +
// lane*16 (m104/m108); per-lane scatter impossible -> XOR chunk swizzle.
__device__ __forceinline__ void gl_lds16(const ushort* g, ushort* l) {
    __builtin_amdgcn_global_load_lds(
        (const __attribute__((address_space(1))) unsigned int*)g,
        (__attribute__((address_space(3))) unsigned int*)l, 16, 0, 0);
}

// ---------------------------------------------------------------------------
// fp16 MFMA GEMM:  C = act( A*B + bias ),  fp32 accumulate.
// A [M,K] f16 row-major (over-allocated by 128 rows: OOB tile rows read
// garbage, never fault, confined to C rows >= M which are not stored).
// B TRANSPOSED: BT [N,K] f16, N % BN == 0, K % 64 == 0.
// Block tile 128 x BN, 4 waves; BN=128: wave=64x64 (4x4 frags);
// BN=64: wave=64x32 (4x2 frags). BK=32, double-buffered global_load_lds
// (R8 lesson: VGPR prefetch spills; R7 lesson: single-buffer has zero
// latency overlap). fp16 single-pass replaces R8's 3x split-bf16 MFMA —
// absmax headroom is large (pinned at 2^-13 across fp32 AND split rounds).
// Swizzle: 16B chunk c of row r stored at slot c^((r>>2)&3).
template<int BN>
__global__ __launch_bounds__(256) void gemm_f16(
    const ushort* __restrict__ A, const ushort* __restrict__ BT,
    const float* __restrict__ bias,
    float* __restrict__ Cf, ushort* __restrict__ Ch,
    int M, int N, int K, int relu)
{
    constexpr int NI  = BN / 32;            // N-frags per wave
    constexpr int BUF = 4096 + BN * 32;     // halfs per buffer
    __shared__ ushort lds[2 * BUF];
    ushort* buf0 = lds;
    ushort* buf1 = lds + BUF;

    const int t = threadIdx.x;
    const int l = t & 63;
    const int w = t >> 6;
    const int wm = (w >> 1) * 64;           // wave M offset
    const int wn = (w & 1) * (BN / 2);      // wave N offset
    const int lm = l & 15;
    const int q  = l >> 4;                  // k-chunk id (0..3)
    const int q4 = q * 4;                   // C frag row offset

    const int row0 = blockIdx.x * 128;
    const int col0 = blockIdx.y * BN;

    // Staging: instruction (j,w) covers LDS chunks (j*4+w)*64..+64 = rows
    // (j*4+w)*16..+16. Lane l -> row += l>>2, slot l&3; global chunk =
    // (l&3) ^ ((row>>2)&3) = (l&3) ^ ((l>>4)&3)  (row base mult of 16).
    const int jr0 = w * 16 + (l >> 2);
    const int gsh = (((l & 3) ^ ((l >> 4) & 3)) << 3);   // half offset
    const ushort* gA0 = A + (size_t)(row0 + jr0) * K + gsh;
    const ushort* gA1 = gA0 + (size_t)64 * K;
    const ushort* gB0 = BT + (size_t)(col0 + jr0) * K + gsh;
    const ushort* gB1 = gB0 + (size_t)64 * K;            // BN=128 only
    const int dA0 = w * 512, dA1 = (4 + w) * 512;
    const int dB0 = 4096 + w * 512, dB1 = 4096 + (4 + w) * 512;

    // frag-read swizzle: row = 16*a + lm -> slot q ^ ((lm>>2)&3)
    const int csw = ((q ^ ((lm >> 2) & 3)) << 3);

    const f32x4 zf = {0.f, 0.f, 0.f, 0.f};
    f32x4 acc[4][NI];
    #pragma unroll
    for (int i = 0; i < 4; ++i)
        #pragma unroll
        for (int j = 0; j < NI; ++j) acc[i][j] = zf;

    auto issue = [&](int kk, ushort* B) {
        gl_lds16(gA0 + kk, B + dA0);
        gl_lds16(gA1 + kk, B + dA1);
        gl_lds16(gB0 + kk, B + dB0);
        if (BN == 128) gl_lds16(gB1 + kk, B + dB1);
    };

    auto compute = [&](const ushort* B) {
        half8 bf[NI];
        #pragma unroll
        for (int ni = 0; ni < NI; ++ni) {
            const int boff = (wn + ni * 16 + lm) * 32 + csw;
            bf[ni] = *(const half8*)&B[4096 + boff];
        }
        #pragma unroll
        for (int mi = 0; mi < 4; ++mi) {
            const int aoff = (wm + mi * 16 + lm) * 32 + csw;
            half8 af = *(const half8*)&B[aoff];
            #pragma unroll
            for (int ni = 0; ni < NI; ++ni)
                acc[mi][ni] = __builtin_amdgcn_mfma_f32_16x16x32_f16(
                    af, bf[ni], acc[mi][ni], 0, 0, 0);
        }
    };

    // Pipelined K-loop: next tile's DMA in flight during current MFMAs.
    issue(0, buf0);
    __syncthreads();
    for (int k0 = 0; k0 < K; k0 += 64) {
        issue(k0 + 32, buf1);
        compute(buf0);
        __syncthreads();
        if (k0 + 64 < K) issue(k0 + 64, buf0);
        compute(buf1);
        __syncthreads();
    }

    // Epilogue. C/D frag: col = lane&15, row = (lane>>4)*4 + reg  [m89/m91]
    #pragma unroll
    for (int mi = 0; mi < 4; ++mi) {
        #pragma unroll
        for (int ni = 0; ni < NI; ++ni) {
            const int col = col0 + wn + ni * 16 + lm;
            const float bv = bias ? bias[col] : 0.f;
            #pragma unroll
            for (int r = 0; r < 4; ++r) {
                const int row = row0 + wm + mi * 16 + q4 + r;
                if (row >= M) continue;
                float v = acc[mi][ni][r] + bv;
                if (relu) v = fmaxf(v, 0.f);
                const size_t idx = (size_t)row * N + col;
                if (Cf) Cf[idx] = v;
                if (Ch) Ch[idx] = f2h(v);
            }
        }
    }
}

// ---------------------------------------------------------------------------
// Elementwise fp32 -> f16 (vectorized x4)
__global__ __launch_bounds__(256) void cvt_kernel(
    const float* __restrict__ x, ushort* __restrict__ o, int n4)
{
    int i = blockIdx.x * 256 + threadIdx.x;
    if (i >= n4) return;
    float4 v = ((const float4*)x)[i];
    ((ushort4*)o)[i] = make_ushort4(f2h(v.x), f2h(v.y), f2h(v.z), f2h(v.w));
}

// ---------------------------------------------------------------------------
// W [K,N] fp32 -> WT [N,K] f16 (transpose + convert; tiny matrices)
__global__ __launch_bounds__(256) void transpose_cvt_kernel(
    const float* __restrict__ W, ushort* __restrict__ T, int K, int N)
{
    int i = blockIdx.x * 256 + threadIdx.x;
    if (i >= K * N) return;
    int k = i / N, n = i - k * N;
    T[(size_t)n * K + k] = f2h(W[i]);
}

// ---------------------------------------------------------------------------
// a_src[n,h] = dot(xp[n,h,:], att_src[h,:]); a_dst likewise. xp is f16.
__global__ __launch_bounds__(256) void att_kernel(
    const ushort* __restrict__ xp, const float* __restrict__ att_src,
    const float* __restrict__ att_dst,
    float* __restrict__ a_src, float* __restrict__ a_dst, int n)
{
    int gw = (blockIdx.x * blockDim.x + threadIdx.x) >> 6;
    int lane = threadIdx.x & 63;
    if (gw >= 2 * n) return;
    int node = gw >> 1, h = gw & 1;
    const ushort* row = xp + (size_t)node * HC + h * OUT_C;
    const float* as = att_src + h * OUT_C;
    const float* ad = att_dst + h * OUT_C;
    float r0 = h2f(row[lane]), r1 = h2f(row[lane + 64]);
    float s1 = r0 * as[lane] + r1 * as[lane + 64];
    float s2 = r0 * ad[lane] + r1 * ad[lane + 64];
    #pragma unroll
    for (int off = 32; off > 0; off >>= 1) {
        s1 += __shfl_down(s1, off);
        s2 += __shfl_down(s2, off);
    }
    if (lane == 0) { a_src[gw] = s1; a_dst[gw] = s2; }
}

// ---------------------------------------------------------------------------
__global__ void zero_int2(int* deg, int* cursor, int n)
{
    int i = blockIdx.x * blockDim.x + threadIdx.x;
    if (i < n) { deg[i] = 0; cursor[i] = 0; }
}

__global__ __launch_bounds__(256) void hist_kernel(
    const int* __restrict__ dst, int* deg, int E_real, int ET)
{
    int e = blockIdx.x * blockDim.x + threadIdx.x;
    if (e >= ET) return;
    int d = (e < E_real) ? dst[e] : (e - E_real);
    atomicAdd(&deg[d], 1);
}

// Exclusive scan deg[0..n) -> rowptr[0..n]; single block, 256 threads.
__global__ __launch_bounds__(256) void scan_kernel(
    const int* __restrict__ deg, int* __restrict__ rowptr, int n)
{
    __shared__ int part[256];
    const int t = threadIdx.x;
    const int chunk = (n + 255) / 256;
    const int lo = t * chunk;
    const int hi = min(lo + chunk, n);
    int s = 0;
    for (int i = lo; i < hi; ++i) s += deg[i];
    part[t] = s;
    __syncthreads();
    #pragma unroll
    for (int off = 1; off < 256; off <<= 1) {
        int add = (t >= off) ? part[t - off] : 0;
        __syncthreads();
        part[t] += add;
        __syncthreads();
    }
    int run = part[t] - s;   // exclusive prefix of this thread's chunk
    for (int i = lo; i < hi; ++i) { rowptr[i] = run; run += deg[i]; }
    if (t == 255) rowptr[n] = part[255];
}

__global__ __launch_bounds__(256) void scatter_kernel(
    const int* __restrict__ src, const int* __restrict__ dst,
    const int* __restrict__ rowptr, int* cursor,
    int* __restrict__ sorted_src, int E_real, int ET)
{
    int e = blockIdx.x * blockDim.x + threadIdx.x;
    if (e >= ET) return;
    int s, d;
    if (e < E_real) { s = src[e]; d = dst[e]; }
    else            { s = e - E_real; d = s; }
    int pos = rowptr[d] + atomicAdd(&cursor[d], 1);
    sorted_src[pos] = s;
}

// ---------------------------------------------------------------------------
// One WAVE per dst node; lane owns 4 channels; head = lane>>5. xp is f16
// (ushort4 gather = 8 B/lane, 512 B coalesced per row). Emits xg f16.
__global__ __launch_bounds__(64) void gat_aggregate(
    const int* __restrict__ rowptr, const int* __restrict__ sorted_src,
    const float* __restrict__ a_src, const float* __restrict__ a_dst,
    const ushort* __restrict__ xp, const float* __restrict__ bias_g,
    ushort* __restrict__ xg)
{
    __shared__ float s_w[2][64];
    __shared__ int   s_off[64];

    const int d = blockIdx.x;
    const int lane = threadIdx.x;
    const int h = lane >> 5;
    const int start = rowptr[d], end = rowptr[d + 1];

    const float ad0 = a_dst[2 * d + 0];
    const float ad1 = a_dst[2 * d + 1];

    float m0 = -FLT_MAX, m1 = -FLT_MAX;
    for (int e = start + lane; e < end; e += 64) {
        int s = sorted_src[e];
        float v0 = a_src[2 * s + 0] + ad0;
        float v1 = a_src[2 * s + 1] + ad1;
        v0 = (v0 > 0.f) ? v0 : NEG_SLOPE * v0;
        v1 = (v1 > 0.f) ? v1 : NEG_SLOPE * v1;
        m0 = fmaxf(m0, v0);
        m1 = fmaxf(m1, v1);
    }
    #pragma unroll
    for (int off = 32; off > 0; off >>= 1) {
        m0 = fmaxf(m0, __shfl_xor(m0, off));
        m1 = fmaxf(m1, __shfl_xor(m1, off));
    }

    float4 acc = make_float4(0.f, 0.f, 0.f, 0.f);
    float denom = 0.f;
    for (int e0 = start; e0 < end; e0 += 64) {
        int cnt = min(64, end - e0);
        if (lane < cnt) {
            int s = sorted_src[e0 + lane];
            float v0 = a_src[2 * s + 0] + ad0;
            float v1 = a_src[2 * s + 1] + ad1;
            v0 = (v0 > 0.f) ? v0 : NEG_SLOPE * v0;
            v1 = (v1 > 0.f) ? v1 : NEG_SLOPE * v1;
            s_w[0][lane] = expf(v0 - m0);
            s_w[1][lane] = expf(v1 - m1);
            s_off[lane] = s * HC;
        }
        __syncthreads();
        for (int j = 0; j < cnt; ++j) {
            float w = s_w[h][j];
            const ushort4 v = *(const ushort4*)(xp + s_off[j] + 4 * lane);
            denom += w;
            acc.x += w * h2f(v.x); acc.y += w * h2f(v.y);
            acc.z += w * h2f(v.z); acc.w += w * h2f(v.w);
        }
        __syncthreads();
    }

    float inv = 1.f / fmaxf(denom, 1e-16f);
    int c = 4 * lane;
    float4 bg = *(const float4*)(bias_g + c);
    const size_t base = ((size_t)d * HC + c) >> 2;
    ((ushort4*)xg)[base] = make_ushort4(
        f2h(acc.x * inv + bg.x), f2h(acc.y * inv + bg.y),
        f2h(acc.z * inv + bg.z), f2h(acc.w * inv + bg.w));
}

// ---------------------------------------------------------------------------
extern "C" void kernel_launch(void* const* d_in, const int* in_sizes, int n_in,
                              void* d_out, int out_size, void* d_ws, size_t ws_size,
                              hipStream_t stream)
{
    const float* z       = (const float*)d_in[0];
    const int*   ei      = (const int*)d_in[1];    // [2,E] int32
    const float* W1      = (const float*)d_in[2];
    const float* b1      = (const float*)d_in[3];
    const float* W2      = (const float*)d_in[4];
    const float* b2      = (const float*)d_in[5];
    const float* Wg      = (const float*)d_in[6];
    const float* att_src = (const float*)d_in[7];
    const float* att_dst = (const float*)d_in[8];
    const float* bias_g  = (const float*)d_in[9];
    const float* W3      = (const float*)d_in[10];
    const float* b3      = (const float*)d_in[11];
    float* out = (float*)d_out;

    const int n = N_NODES;
    const int E_real = in_sizes[1] / 2;
    const int ET = E_real + n;
    const int* src = ei;
    const int* dst = ei + E_real;

    // Workspace. GEMM-A arrays over-allocated by 128 rows (DMA staging of
    // the last partial tile reads garbage, never faults).
    // Aliases: z_f16 (dead after GEMM1) = x2_f16; x1_f16 (dead after GEMM2) = xg.
    char* p = (char*)d_ws;
    auto alloc = [&](size_t bytes) {
        char* r = p;
        p += (bytes + 63) & ~(size_t)63;
        return r;
    };
    const int np = n + 128;
    ushort* z_f16  = (ushort*)alloc((size_t)np * LATENT * 2);  // 20.6 MB
    ushort* x1_f16 = (ushort*)alloc((size_t)np * HID * 2);     // 10.3 MB
    ushort* xp_f16 = (ushort*)alloc((size_t)n * HC * 2);       // 10.2 MB
    ushort* W1T = (ushort*)alloc((size_t)LATENT * HID * 2);
    ushort* W2T = (ushort*)alloc((size_t)HID * 512 * 2);
    ushort* WgT = (ushort*)alloc((size_t)512 * HC * 2);
    ushort* W3T = (ushort*)alloc((size_t)HC * 512 * 2);
    float* a_src = (float*)alloc((size_t)2 * n * 4);
    float* a_dst = (float*)alloc((size_t)2 * n * 4);
    int* deg        = (int*)alloc((size_t)n * 4);
    int* rowptr     = (int*)alloc(((size_t)n + 1) * 4);
    int* cursor     = (int*)alloc((size_t)n * 4);
    int* sorted_src = (int*)alloc((size_t)ET * 4);
    ushort* x2_f16 = z_f16;    // reuse (512 halfs/row, same as z)
    ushort* xg_f16 = x1_f16;   // reuse (256 halfs/row, same as x1)

    const int gm128 = (n + 127) / 128;   // 157

    // prologue: convert input + weights to f16 (weights transposed)
    cvt_kernel<<<(n * LATENT / 4 + 255) / 256, 256, 0, stream>>>(
        z, z_f16, n * LATENT / 4);
    transpose_cvt_kernel<<<(LATENT * HID + 255) / 256, 256, 0, stream>>>(
        W1, W1T, LATENT, HID);
    transpose_cvt_kernel<<<(HID * 512 + 255) / 256, 256, 0, stream>>>(
        W2, W2T, HID, 512);
    transpose_cvt_kernel<<<(512 * HC + 255) / 256, 256, 0, stream>>>(
        Wg, WgT, 512, HC);
    transpose_cvt_kernel<<<(HC * 512 + 255) / 256, 256, 0, stream>>>(
        W3, W3T, HC, 512);

    // GEMM1: x1 = relu(z @ W1 + b1)   [20000,512]x[512,256]  BN=64: 628 blocks
    gemm_f16<64><<<dim3(gm128, HID / 64), 256, 0, stream>>>(
        z_f16, W1T, b1, nullptr, x1_f16, n, HID, LATENT, 1);
    // GEMM2: x2 = relu(x1 @ W2 + b2)  [20000,256]x[256,512]  BN=128
    gemm_f16<128><<<dim3(gm128, 512 / 128), 256, 0, stream>>>(
        x1_f16, W2T, b2, nullptr, x2_f16, n, 512, HID, 1);
    // GEMM3: xp = x2 @ Wg             [20000,512]x[512,256]  BN=64
    gemm_f16<64><<<dim3(gm128, HC / 64), 256, 0, stream>>>(
        x2_f16, WgT, nullptr, nullptr, xp_f16, n, HC, 512, 0);

    // attention logits (f16 xp)
    att_kernel<<<(2 * n + 3) / 4, 256, 0, stream>>>(
        xp_f16, att_src, att_dst, a_src, a_dst, n);
    // CSR build
    zero_int2<<<(n + 255) / 256, 256, 0, stream>>>(deg, cursor, n);
    hist_kernel<<<(ET + 255) / 256, 256, 0, stream>>>(dst, deg, E_real, ET);
    scan_kernel<<<1, 256, 0, stream>>>(deg, rowptr, n);
    scatter_kernel<<<(ET + 255) / 256, 256, 0, stream>>>(
        src, dst, rowptr, cursor, sorted_src, E_real, ET);
    // softmax + aggregate -> xg (f16)
    gat_aggregate<<<n, 64, 0, stream>>>(
        rowptr, sorted_src, a_src, a_dst, xp_f16, bias_g, xg_f16);

    // GEMM4: out = xg @ W3 + b3       [20000,256]x[256,512]  BN=128 -> fp32
    gemm_f16<128><<<dim3(gm128, 512 / 128), 256, 0, stream>>>(
        xg_f16, W3T, b3, out, nullptr, n, 512, HC, 0);
}

// Round 11
// 338.496 us; speedup vs baseline: 1.7141x; 1.0365x over previous
//
#include <hip/hip_runtime.h>
#include <hip/hip_bf16.h>
#include <float.h>

// Problem constants (from reference)
#define N_NODES 20000
#define LATENT  512
#define HID     256
#define OUT_C   128
#define HEADS   2
#define HC      256   // HEADS*OUT_C
#define NEG_SLOPE 0.2f

typedef _Float16 half8 __attribute__((ext_vector_type(8)));  // 8 f16 = 4 VGPRs
typedef __attribute__((ext_vector_type(4))) float f32x4;

// ---------------------------------------------------------------------------
__device__ __forceinline__ ushort f2h(float v) {
    _Float16 h = (_Float16)v;
    return *(ushort*)&h;
}
__device__ __forceinline__ float h2f(ushort u) {
    _Float16 h = *(_Float16*)&u;
    return (float)h;
}

// async global->LDS DMA, 16B per lane. LDS dest is WAVE-UNIFORM base +
// lane*16 (m104/m108); per-lane scatter impossible -> XOR chunk swizzle.
__device__ __forceinline__ void gl_lds16(const ushort* g, ushort* l) {
    __builtin_amdgcn_global_load_lds(
        (const __attribute__((address_space(1))) unsigned int*)g,
        (__attribute__((address_space(3))) unsigned int*)l, 16, 0, 0);
}

// ---------------------------------------------------------------------------
// fp16 MFMA GEMM:  C = act( A*B + bias ),  fp32 accumulate.
// A [M,K] f16 row-major (over-allocated by 128 rows: OOB tile rows read
// garbage, never fault, confined to C rows >= M which are not stored).
// B TRANSPOSED: BT [N,K] f16, N % BN == 0, K % 64 == 0.
// Block tile 128 x BN, 4 waves; BN=128: wave=64x64; BN=64: wave=64x32.
// BK=32, double-buffered global_load_lds (R8: VGPR prefetch spills;
// R7: single-buffer = zero latency overlap). R10: BN=64 for the N=512
// GEMMs too — 1256 blocks (~5/CU) for TLP latency hiding.
// Swizzle: 16B chunk c of row r stored at slot c^((r>>2)&3).
template<int BN>
__global__ __launch_bounds__(256) void gemm_f16(
    const ushort* __restrict__ A, const ushort* __restrict__ BT,
    const float* __restrict__ bias,
    float* __restrict__ Cf, ushort* __restrict__ Ch,
    int M, int N, int K, int relu)
{
    constexpr int NI  = BN / 32;            // N-frags per wave
    constexpr int BUF = 4096 + BN * 32;     // halfs per buffer
    __shared__ ushort lds[2 * BUF];
    ushort* buf0 = lds;
    ushort* buf1 = lds + BUF;

    const int t = threadIdx.x;
    const int l = t & 63;
    const int w = t >> 6;
    const int wm = (w >> 1) * 64;           // wave M offset
    const int wn = (w & 1) * (BN / 2);      // wave N offset
    const int lm = l & 15;
    const int q  = l >> 4;                  // k-chunk id (0..3)
    const int q4 = q * 4;                   // C frag row offset

    const int row0 = blockIdx.x * 128;
    const int col0 = blockIdx.y * BN;

    // Staging: instruction (j,w) covers LDS chunks (j*4+w)*64..+64 = rows
    // (j*4+w)*16..+16. Lane l -> row += l>>2, slot l&3; global chunk =
    // (l&3) ^ ((row>>2)&3) = (l&3) ^ ((l>>4)&3)  (row base mult of 16).
    const int jr0 = w * 16 + (l >> 2);
    const int gsh = (((l & 3) ^ ((l >> 4) & 3)) << 3);   // half offset
    const ushort* gA0 = A + (size_t)(row0 + jr0) * K + gsh;
    const ushort* gA1 = gA0 + (size_t)64 * K;
    const ushort* gB0 = BT + (size_t)(col0 + jr0) * K + gsh;
    const ushort* gB1 = gB0 + (size_t)64 * K;            // BN=128 only
    const int dA0 = w * 512, dA1 = (4 + w) * 512;
    const int dB0 = 4096 + w * 512, dB1 = 4096 + (4 + w) * 512;

    // frag-read swizzle: row = 16*a + lm -> slot q ^ ((lm>>2)&3)
    const int csw = ((q ^ ((lm >> 2) & 3)) << 3);

    const f32x4 zf = {0.f, 0.f, 0.f, 0.f};
    f32x4 acc[4][NI];
    #pragma unroll
    for (int i = 0; i < 4; ++i)
        #pragma unroll
        for (int j = 0; j < NI; ++j) acc[i][j] = zf;

    auto issue = [&](int kk, ushort* B) {
        gl_lds16(gA0 + kk, B + dA0);
        gl_lds16(gA1 + kk, B + dA1);
        gl_lds16(gB0 + kk, B + dB0);
        if (BN == 128) gl_lds16(gB1 + kk, B + dB1);
    };

    auto compute = [&](const ushort* B) {
        half8 bf[NI];
        #pragma unroll
        for (int ni = 0; ni < NI; ++ni) {
            const int boff = (wn + ni * 16 + lm) * 32 + csw;
            bf[ni] = *(const half8*)&B[4096 + boff];
        }
        #pragma unroll
        for (int mi = 0; mi < 4; ++mi) {
            const int aoff = (wm + mi * 16 + lm) * 32 + csw;
            half8 af = *(const half8*)&B[aoff];
            #pragma unroll
            for (int ni = 0; ni < NI; ++ni)
                acc[mi][ni] = __builtin_amdgcn_mfma_f32_16x16x32_f16(
                    af, bf[ni], acc[mi][ni], 0, 0, 0);
        }
    };

    // Pipelined K-loop: next tile's DMA in flight during current MFMAs.
    issue(0, buf0);
    __syncthreads();
    for (int k0 = 0; k0 < K; k0 += 64) {
        issue(k0 + 32, buf1);
        compute(buf0);
        __syncthreads();
        if (k0 + 64 < K) issue(k0 + 64, buf0);
        compute(buf1);
        __syncthreads();
    }

    // Epilogue. C/D frag: col = lane&15, row = (lane>>4)*4 + reg  [m89/m91]
    #pragma unroll
    for (int mi = 0; mi < 4; ++mi) {
        #pragma unroll
        for (int ni = 0; ni < NI; ++ni) {
            const int col = col0 + wn + ni * 16 + lm;
            const float bv = bias ? bias[col] : 0.f;
            #pragma unroll
            for (int r = 0; r < 4; ++r) {
                const int row = row0 + wm + mi * 16 + q4 + r;
                if (row >= M) continue;
                float v = acc[mi][ni][r] + bv;
                if (relu) v = fmaxf(v, 0.f);
                const size_t idx = (size_t)row * N + col;
                if (Cf) Cf[idx] = v;
                if (Ch) Ch[idx] = f2h(v);
            }
        }
    }
}

// ---------------------------------------------------------------------------
// fp32 -> f16 convert (x4) + fused zeroing of deg/cursor (independent data)
__global__ __launch_bounds__(256) void cvt_zero_kernel(
    const float* __restrict__ x, ushort* __restrict__ o, int n4,
    int* deg, int* cursor, int n)
{
    int i = blockIdx.x * 256 + threadIdx.x;
    if (i < n) { deg[i] = 0; cursor[i] = 0; }
    if (i >= n4) return;
    float4 v = ((const float4*)x)[i];
    ((ushort4*)o)[i] = make_ushort4(f2h(v.x), f2h(v.y), f2h(v.z), f2h(v.w));
}

// ---------------------------------------------------------------------------
// All 4 weights: W [K,N] fp32 -> WT [N,K] f16 in ONE launch.
// Each W has K*N = 131072 = 2^17 elements.
__global__ __launch_bounds__(256) void transpose_cvt4_kernel(
    const float* __restrict__ W1, const float* __restrict__ W2,
    const float* __restrict__ Wg, const float* __restrict__ W3,
    ushort* __restrict__ T1, ushort* __restrict__ T2,
    ushort* __restrict__ Tg, ushort* __restrict__ T3)
{
    int idx = blockIdx.x * 256 + threadIdx.x;
    int which = idx >> 17, i = idx & 131071;
    const float* W; ushort* T; int K, N;
    if (which == 0)      { W = W1; T = T1; K = 512; N = 256; }
    else if (which == 1) { W = W2; T = T2; K = 256; N = 512; }
    else if (which == 2) { W = Wg; T = Tg; K = 512; N = 256; }
    else                 { W = W3; T = T3; K = 256; N = 512; }
    int k = i / N, n = i - k * N;
    T[(size_t)n * K + k] = f2h(W[i]);
}

// ---------------------------------------------------------------------------
// One WAVE per node (R10: was one wave per node*head with 2B scalar loads).
// Lane l: head h=l>>5, 4 channels c=h*128+(l&31)*4 via ushort4 (8B/lane).
// Half-wave shuffle reduce (xor offsets < 32 stay within the 32-lane group).
__global__ __launch_bounds__(256) void att_kernel(
    const ushort* __restrict__ xp, const float* __restrict__ att_src,
    const float* __restrict__ att_dst,
    float* __restrict__ a_src, float* __restrict__ a_dst, int n)
{
    int node = (blockIdx.x * 256 + threadIdx.x) >> 6;
    int lane = threadIdx.x & 63;
    if (node >= n) return;
    int h = lane >> 5, lh = lane & 31;
    int c = h * OUT_C + lh * 4;
    const ushort4 v = *(const ushort4*)(xp + (size_t)node * HC + c);
    const float4 as = *(const float4*)(att_src + c);
    const float4 ad = *(const float4*)(att_dst + c);
    float x0 = h2f(v.x), x1 = h2f(v.y), x2 = h2f(v.z), x3 = h2f(v.w);
    float s1 = x0 * as.x + x1 * as.y + x2 * as.z + x3 * as.w;
    float s2 = x0 * ad.x + x1 * ad.y + x2 * ad.z + x3 * ad.w;
    #pragma unroll
    for (int off = 16; off > 0; off >>= 1) {
        s1 += __shfl_xor(s1, off);
        s2 += __shfl_xor(s2, off);
    }
    if (lh == 0) { a_src[2 * node + h] = s1; a_dst[2 * node + h] = s2; }
}

// ---------------------------------------------------------------------------
__global__ __launch_bounds__(256) void hist_kernel(
    const int* __restrict__ dst, int* deg, int E_real, int ET)
{
    int e = blockIdx.x * blockDim.x + threadIdx.x;
    if (e >= ET) return;
    int d = (e < E_real) ? dst[e] : (e - E_real);
    atomicAdd(&deg[d], 1);
}

// Exclusive scan deg[0..n) -> rowptr[0..n]; single block, 256 threads.
__global__ __launch_bounds__(256) void scan_kernel(
    const int* __restrict__ deg, int* __restrict__ rowptr, int n)
{
    __shared__ int part[256];
    const int t = threadIdx.x;
    const int chunk = (n + 255) / 256;
    const int lo = t * chunk;
    const int hi = min(lo + chunk, n);
    int s = 0;
    for (int i = lo; i < hi; ++i) s += deg[i];
    part[t] = s;
    __syncthreads();
    #pragma unroll
    for (int off = 1; off < 256; off <<= 1) {
        int add = (t >= off) ? part[t - off] : 0;
        __syncthreads();
        part[t] += add;
        __syncthreads();
    }
    int run = part[t] - s;   // exclusive prefix of this thread's chunk
    for (int i = lo; i < hi; ++i) { rowptr[i] = run; run += deg[i]; }
    if (t == 255) rowptr[n] = part[255];
}

__global__ __launch_bounds__(256) void scatter_kernel(
    const int* __restrict__ src, const int* __restrict__ dst,
    const int* __restrict__ rowptr, int* cursor,
    int* __restrict__ sorted_src, int E_real, int ET)
{
    int e = blockIdx.x * blockDim.x + threadIdx.x;
    if (e >= ET) return;
    int s, d;
    if (e < E_real) { s = src[e]; d = dst[e]; }
    else            { s = e - E_real; d = s; }
    int pos = rowptr[d] + atomicAdd(&cursor[d], 1);
    sorted_src[pos] = s;
}

// ---------------------------------------------------------------------------
// One WAVE per dst node; lane owns 4 channels; head = lane>>5. xp is f16
// (ushort4 gather = 8 B/lane, 512 B coalesced per row). Emits xg f16.
__global__ __launch_bounds__(64) void gat_aggregate(
    const int* __restrict__ rowptr, const int* __restrict__ sorted_src,
    const float* __restrict__ a_src, const float* __restrict__ a_dst,
    const ushort* __restrict__ xp, const float* __restrict__ bias_g,
    ushort* __restrict__ xg)
{
    __shared__ float s_w[2][64];
    __shared__ int   s_off[64];

    const int d = blockIdx.x;
    const int lane = threadIdx.x;
    const int h = lane >> 5;
    const int start = rowptr[d], end = rowptr[d + 1];

    const float ad0 = a_dst[2 * d + 0];
    const float ad1 = a_dst[2 * d + 1];

    float m0 = -FLT_MAX, m1 = -FLT_MAX;
    for (int e = start + lane; e < end; e += 64) {
        int s = sorted_src[e];
        float v0 = a_src[2 * s + 0] + ad0;
        float v1 = a_src[2 * s + 1] + ad1;
        v0 = (v0 > 0.f) ? v0 : NEG_SLOPE * v0;
        v1 = (v1 > 0.f) ? v1 : NEG_SLOPE * v1;
        m0 = fmaxf(m0, v0);
        m1 = fmaxf(m1, v1);
    }
    #pragma unroll
    for (int off = 32; off > 0; off >>= 1) {
        m0 = fmaxf(m0, __shfl_xor(m0, off));
        m1 = fmaxf(m1, __shfl_xor(m1, off));
    }

    float4 acc = make_float4(0.f, 0.f, 0.f, 0.f);
    float denom = 0.f;
    for (int e0 = start; e0 < end; e0 += 64) {
        int cnt = min(64, end - e0);
        if (lane < cnt) {
            int s = sorted_src[e0 + lane];
            float v0 = a_src[2 * s + 0] + ad0;
            float v1 = a_src[2 * s + 1] + ad1;
            v0 = (v0 > 0.f) ? v0 : NEG_SLOPE * v0;
            v1 = (v1 > 0.f) ? v1 : NEG_SLOPE * v1;
            s_w[0][lane] = expf(v0 - m0);
            s_w[1][lane] = expf(v1 - m1);
            s_off[lane] = s * HC;
        }
        __syncthreads();
        for (int j = 0; j < cnt; ++j) {
            float w = s_w[h][j];
            const ushort4 v = *(const ushort4*)(xp + s_off[j] + 4 * lane);
            denom += w;
            acc.x += w * h2f(v.x); acc.y += w * h2f(v.y);
            acc.z += w * h2f(v.z); acc.w += w * h2f(v.w);
        }
        __syncthreads();
    }

    float inv = 1.f / fmaxf(denom, 1e-16f);
    int c = 4 * lane;
    float4 bg = *(const float4*)(bias_g + c);
    const size_t base = ((size_t)d * HC + c) >> 2;
    ((ushort4*)xg)[base] = make_ushort4(
        f2h(acc.x * inv + bg.x), f2h(acc.y * inv + bg.y),
        f2h(acc.z * inv + bg.z), f2h(acc.w * inv + bg.w));
}

// ---------------------------------------------------------------------------
extern "C" void kernel_launch(void* const* d_in, const int* in_sizes, int n_in,
                              void* d_out, int out_size, void* d_ws, size_t ws_size,
                              hipStream_t stream)
{
    const float* z       = (const float*)d_in[0];
    const int*   ei      = (const int*)d_in[1];    // [2,E] int32
    const float* W1      = (const float*)d_in[2];
    const float* b1      = (const float*)d_in[3];
    const float* W2      = (const float*)d_in[4];
    const float* b2      = (const float*)d_in[5];
    const float* Wg      = (const float*)d_in[6];
    const float* att_src = (const float*)d_in[7];
    const float* att_dst = (const float*)d_in[8];
    const float* bias_g  = (const float*)d_in[9];
    const float* W3      = (const float*)d_in[10];
    const float* b3      = (const float*)d_in[11];
    float* out = (float*)d_out;

    const int n = N_NODES;
    const int E_real = in_sizes[1] / 2;
    const int ET = E_real + n;
    const int* src = ei;
    const int* dst = ei + E_real;

    // Workspace. GEMM-A arrays over-allocated by 128 rows (DMA staging of
    // the last partial tile reads garbage, never faults).
    // Aliases: z_f16 (dead after GEMM1) = x2_f16; x1_f16 (dead after GEMM2) = xg.
    char* p = (char*)d_ws;
    auto alloc = [&](size_t bytes) {
        char* r = p;
        p += (bytes + 63) & ~(size_t)63;
        return r;
    };
    const int np = n + 128;
    ushort* z_f16  = (ushort*)alloc((size_t)np * LATENT * 2);  // 20.6 MB
    ushort* x1_f16 = (ushort*)alloc((size_t)np * HID * 2);     // 10.3 MB
    ushort* xp_f16 = (ushort*)alloc((size_t)n * HC * 2);       // 10.2 MB
    ushort* W1T = (ushort*)alloc((size_t)LATENT * HID * 2);
    ushort* W2T = (ushort*)alloc((size_t)HID * 512 * 2);
    ushort* WgT = (ushort*)alloc((size_t)512 * HC * 2);
    ushort* W3T = (ushort*)alloc((size_t)HC * 512 * 2);
    float* a_src = (float*)alloc((size_t)2 * n * 4);
    float* a_dst = (float*)alloc((size_t)2 * n * 4);
    int* deg        = (int*)alloc((size_t)n * 4);
    int* rowptr     = (int*)alloc(((size_t)n + 1) * 4);
    int* cursor     = (int*)alloc((size_t)n * 4);
    int* sorted_src = (int*)alloc((size_t)ET * 4);
    ushort* x2_f16 = z_f16;    // reuse (512 halfs/row, same as z)
    ushort* xg_f16 = x1_f16;   // reuse (256 halfs/row, same as x1)

    const int gm128 = (n + 127) / 128;   // 157

    // prologue: z->f16 (+ fused deg/cursor zero), 4 weight transposes fused
    cvt_zero_kernel<<<(n * LATENT / 4 + 255) / 256, 256, 0, stream>>>(
        z, z_f16, n * LATENT / 4, deg, cursor, n);
    transpose_cvt4_kernel<<<(4 * 131072) / 256, 256, 0, stream>>>(
        W1, W2, Wg, W3, W1T, W2T, WgT, W3T);

    // GEMM1: x1 = relu(z @ W1 + b1)   [20000,512]x[512,256]  (157,4)
    gemm_f16<64><<<dim3(gm128, HID / 64), 256, 0, stream>>>(
        z_f16, W1T, b1, nullptr, x1_f16, n, HID, LATENT, 1);
    // GEMM2: x2 = relu(x1 @ W2 + b2)  [20000,256]x[256,512]  (157,8)
    gemm_f16<64><<<dim3(gm128, 512 / 64), 256, 0, stream>>>(
        x1_f16, W2T, b2, nullptr, x2_f16, n, 512, HID, 1);
    // GEMM3: xp = x2 @ Wg             [20000,512]x[512,256]  (157,4)
    gemm_f16<64><<<dim3(gm128, HC / 64), 256, 0, stream>>>(
        x2_f16, WgT, nullptr, nullptr, xp_f16, n, HC, 512, 0);

    // attention logits (one wave per node, vectorized)
    att_kernel<<<(n * 64 + 255) / 256, 256, 0, stream>>>(
        xp_f16, att_src, att_dst, a_src, a_dst, n);
    // CSR build (deg/cursor already zeroed in cvt_zero_kernel)
    hist_kernel<<<(ET + 255) / 256, 256, 0, stream>>>(dst, deg, E_real, ET);
    scan_kernel<<<1, 256, 0, stream>>>(deg, rowptr, n);
    scatter_kernel<<<(ET + 255) / 256, 256, 0, stream>>>(
        src, dst, rowptr, cursor, sorted_src, E_real, ET);
    // softmax + aggregate -> xg (f16)
    gat_aggregate<<<n, 64, 0, stream>>>(
        rowptr, sorted_src, a_src, a_dst, xp_f16, bias_g, xg_f16);

    // GEMM4: out = xg @ W3 + b3       [20000,256]x[256,512]  (157,8) -> fp32
    gemm_f16<64><<<dim3(gm128, 512 / 64), 256, 0, stream>>>(
        xg_f16, W3T, b3, out, nullptr, n, 512, HC, 0);
}